// Round 26
// baseline (115.930 us; speedup 1.0000x reference)
//
#include <hip/hip_runtime.h>
#include <math.h>

#define CIN  256
#define COUT 128
#define HW   4096
#define NB   4
#define OCSPLIT 4
#define CSPLIT  2
#define CPC  (CIN / CSPLIT)      // 128 channels per k_dcn block (4 chunks of 32)
#define SFLAV (576 * 16)         // u32 words in k_dcn sbuf (hi flavor only)

typedef short short8v __attribute__((ext_vector_type(8)));
typedef float f32x4  __attribute__((ext_vector_type(4)));

// ---------------- weight prep (DCN): bf16 hi/lo split, fragment-ready layout
__global__ __launch_bounds__(256) void k_prep_w(
    const float* __restrict__ w_dcn, const float* __restrict__ b_dcn,
    const float* __restrict__ gamma, const float* __restrict__ beta,
    const float* __restrict__ rmean, const float* __restrict__ rvar,
    unsigned short* __restrict__ w_hi, unsigned short* __restrict__ w_lo,
    float* __restrict__ bias_t)
{
  int t = blockIdx.x * 256 + threadIdx.x;
  if (t < COUT) {
    float sc = gamma[t] * rsqrtf(rvar[t] + 1e-5f);
    bias_t[t] = b_dcn[t] * sc + beta[t] - rmean[t] * sc;
  }
  if (t >= CIN * COUT * 9) return;
  int k = t % 9;
  int q = t / 9;
  int co = q % COUT;
  int c  = q / COUT;
  float sc = gamma[co] * rsqrtf(rvar[co] + 1e-5f);
  float w = w_dcn[((size_t)co * CIN + c) * 9 + k] * sc;
  unsigned int wb = __float_as_uint(w);
  unsigned short hi = (unsigned short)(wb >> 16);
  float lof = w - __uint_as_float(wb & 0xFFFF0000u);
  unsigned short lo = (unsigned short)(__float_as_uint(lof) >> 16);
  size_t idx = (((size_t)k * 32 + (c >> 3)) * 128 + co) * 8 + (c & 7);
  w_hi[idx] = hi;
  w_lo[idx] = lo;
}

// ---------------- weight prep (offset conv): [k][cq][co32][8ch], co>=27 zero
__global__ __launch_bounds__(256) void k_prep_wo(
    const float* __restrict__ w_off,
    unsigned short* __restrict__ wo_hi, unsigned short* __restrict__ wo_lo)
{
  int t = blockIdx.x * 256 + threadIdx.x;
  if (t >= 9 * 32 * 32 * 8) return;
  int ce = t & 7;
  int co = (t >> 3) & 31;
  int cq = (t >> 8) & 31;
  int k  = t >> 13;
  int c = cq * 8 + ce;
  float w = (co < 27) ? w_off[((size_t)co * CIN + c) * 9 + k] : 0.f;
  unsigned int wb = __float_as_uint(w);
  unsigned short hi = (unsigned short)(wb >> 16);
  float lof = w - __uint_as_float(wb & 0xFFFF0000u);
  unsigned short lo = (unsigned short)(__float_as_uint(lof) >> 16);
  wo_hi[t] = hi;
  wo_lo[t] = lo;
}

// ---------------- offset conv via MFMA (R20) + XCD swizzle (grid 1024 = 8 x 128)
__global__ __launch_bounds__(256, 4) void k_off_mfma(
    const float* __restrict__ x,
    const unsigned short* __restrict__ wo_hi, const unsigned short* __restrict__ wo_lo,
    float* __restrict__ om_part)
{
  int blk = (blockIdx.x & 7) * 128 + (blockIdx.x >> 3);  // bijective: 1024 = 8*128
  int split = blk & 3;
  int bh = blk >> 2;
  int b = bh >> 6, h = bh & 63;
  int t = threadIdx.x;
  int lane = t & 63;
  int wv = t >> 6;
  int lrow = lane & 15, lgrp = lane >> 4;

  __shared__ __align__(16) unsigned int win_hi[3 * 66 * 20];
  __shared__ __align__(16) unsigned int win_lo[3 * 66 * 20];

  f32x4 acc[2];
  acc[0] = (f32x4){0.f, 0.f, 0.f, 0.f};
  acc[1] = (f32x4){0.f, 0.f, 0.f, 0.f};

  const float* xb = x + (size_t)b * CIN * HW;

  for (int chunk = 0; chunk < 2; ++chunk) {
    int cbase = split * 64 + chunk * 32;
    for (int i = t; i < 3168; i += 256) {
      int cp = i / 198;
      int s  = i - cp * 198;
      int r  = s / 66;
      int colp = s - r * 66;
      int row = h + r - 1;
      int col = colp - 1;
      bool v = ((unsigned)row < 64u) && ((unsigned)col < 64u);
      int ch = cbase + 2 * cp;
      float f0 = 0.f, f1 = 0.f;
      if (v) {
        const float* xp = xb + ((size_t)ch * 64 + row) * 64 + col;
        f0 = xp[0];
        f1 = xp[HW];
      }
      unsigned a0 = __float_as_uint(f0), a1 = __float_as_uint(f1);
      unsigned hi = (a0 >> 16) | (a1 & 0xFFFF0000u);
      float l0 = f0 - __uint_as_float(a0 & 0xFFFF0000u);
      float l1 = f1 - __uint_as_float(a1 & 0xFFFF0000u);
      unsigned lo = (__float_as_uint(l0) >> 16) | (__float_as_uint(l1) & 0xFFFF0000u);
      win_hi[s * 20 + cp] = hi;
      win_lo[s * 20 + cp] = lo;
    }
    __syncthreads();

    int pos = wv * 16 + lrow;
#pragma unroll
    for (int k = 0; k < 9; ++k) {
      int ky = k / 3 - 1, kx = k % 3 - 1;
      int slot = (ky + 1) * 66 + pos + kx + 1;
      const unsigned int* ph = &win_hi[slot * 20 + lgrp * 4];
      const unsigned int* pl = &win_lo[slot * 20 + lgrp * 4];
      short8v bh = *(const short8v*)ph;
      short8v bl = *(const short8v*)pl;
#pragma unroll
      for (int m = 0; m < 2; ++m) {
        size_t widx = (((size_t)k * 32 + (cbase >> 3) + lgrp) * 32 + m * 16 + lrow) * 8;
        short8v ah = *(const short8v*)(wo_hi + widx);
        short8v al = *(const short8v*)(wo_lo + widx);
        acc[m] = __builtin_amdgcn_mfma_f32_16x16x32_bf16(ah, bh, acc[m], 0, 0, 0);
        acc[m] = __builtin_amdgcn_mfma_f32_16x16x32_bf16(ah, bl, acc[m], 0, 0, 0);
        acc[m] = __builtin_amdgcn_mfma_f32_16x16x32_bf16(al, bh, acc[m], 0, 0, 0);
      }
    }
    __syncthreads();
  }

  int pos = wv * 16 + lrow;
#pragma unroll
  for (int m = 0; m < 2; ++m)
#pragma unroll
    for (int j = 0; j < 4; ++j) {
      int co = m * 16 + lgrp * 4 + j;
      if (co < 27)
        om_part[(((size_t)split * NB + b) * 27 + co) * HW + h * 64 + pos] = acc[m][j];
    }
}

// ---------------- sampling metadata (sums OCSPLIT=4 partials)
__global__ __launch_bounds__(256) void k_prep_md(
    const float* __restrict__ om_part, const float* __restrict__ b_off,
    float4* __restrict__ md_w, int4* __restrict__ md_i)
{
  int t = blockIdx.x * 256 + threadIdx.x;
  if (t >= NB * 9 * HW) return;
  int hw = t & 4095;
  int bk = t >> 12;
  int k = bk % 9;
  int b = bk / 9;
  int h = hw >> 6, w = hw & 63;

  float dy = b_off[2 * k], dx = b_off[2 * k + 1], mr = b_off[18 + k];
#pragma unroll
  for (int s = 0; s < OCSPLIT; ++s) {
    size_t o = ((size_t)s * NB + b) * 27 * HW + hw;
    dy += om_part[o + (size_t)(2 * k) * HW];
    dx += om_part[o + (size_t)(2 * k + 1) * HW];
    mr += om_part[o + (size_t)(18 + k) * HW];
  }
  float m = 1.0f / (1.0f + expf(-mr));

  int ky = k / 3 - 1, kx = k % 3 - 1;
  float py = dy + (float)h + (float)ky;
  float px = dx + (float)w + (float)kx;
  float y0f = floorf(py), x0f = floorf(px);
  float fy = py - y0f, fx = px - x0f;
  int y0 = (int)y0f, x0 = (int)x0f;
  int y1 = y0 + 1, x1 = x0 + 1;

  bool vy0 = (y0 >= 0) & (y0 < 64), vy1 = (y1 >= 0) & (y1 < 64);
  bool vx0 = (x0 >= 0) & (x0 < 64), vx1 = (x1 >= 0) & (x1 < 64);
  int cy0 = min(max(y0, 0), 63), cy1 = min(max(y1, 0), 63);
  int cx0 = min(max(x0, 0), 63), cx1 = min(max(x1, 0), 63);

  float4 wv;
  wv.x = (vy0 && vx0) ? (1.f - fy) * (1.f - fx) * m : 0.f;
  wv.y = (vy0 && vx1) ? (1.f - fy) * fx * m : 0.f;
  wv.z = (vy1 && vx0) ? fy * (1.f - fx) * m : 0.f;
  wv.w = (vy1 && vx1) ? fy * fx * m : 0.f;
  int4 iv;
  iv.x = cy0 * 64 + cx0;
  iv.y = cy0 * 64 + cx1;
  iv.z = cy1 * 64 + cx0;
  iv.w = cy1 * 64 + cx1;
  md_w[t] = wv;
  md_i[t] = iv;
}

// ---------------- DCN: P=64 channel-last window (DOUBLE-BUFFERED, 1 barrier/step)
// + S rounded bf16 (2-term MFMA) + XCD swizzle. LDS 53248 B.
__global__ __launch_bounds__(256, 3) void k_dcn(
    const float* __restrict__ x,
    const unsigned short* __restrict__ w_hi, const unsigned short* __restrict__ w_lo,
    const float4* __restrict__ md_w, const int4* __restrict__ md_i,
    float* __restrict__ part)
{
  int blk = (blockIdx.x & 7) * 64 + (blockIdx.x >> 3);  // bijective: 512 = 8*64
  int h = blk & 63;
  int b = (blk >> 6) & (NB - 1);
  int s2 = blk >> 8;
  int c0 = s2 * CPC;
  int t = threadIdx.x;
  int lane = t & 63;
  int wv = t >> 6;
  int lrow = lane & 15, lgrp = lane >> 4;

  __shared__ __align__(16) unsigned int sbuf[SFLAV];      // 36864 B (hi only)
  __shared__ __align__(16) float win[2 * 2048];           // 2 x 8192 B dbuf

  int W0 = min(max(h - 3, 0), 56);
  int ob = W0 * 64;

  int k0 = t >> 6;
  size_t mdbase = (size_t)b * 9 * HW;
  size_t mdp = mdbase + (size_t)h * 64 + (t & 63);
  float4 mw0 = md_w[mdp + (size_t)k0 * HW];
  int4  mi0 = md_i[mdp + (size_t)k0 * HW];
  float4 mw1 = md_w[mdp + (size_t)(k0 + 4) * HW];
  int4  mi1 = md_i[mdp + (size_t)(k0 + 4) * HW];
  bool hasC = (t < 64);
  float4 mw2 = make_float4(0.f, 0.f, 0.f, 0.f);
  int4  mi2 = make_int4(0, 0, 0, 0);
  if (hasC) {
    mw2 = md_w[mdp + (size_t)8 * HW];
    mi2 = md_i[mdp + (size_t)8 * HW];
  }
  int fast0 = __all(((unsigned)(mi0.x - ob) < 512u) && ((unsigned)(mi0.z - ob) < 512u));
  int fast1 = __all(((unsigned)(mi1.x - ob) < 512u) && ((unsigned)(mi1.z - ob) < 512u));
  int fast2 = __all(((unsigned)(mi2.x - ob) < 512u) && ((unsigned)(mi2.z - ob) < 512u));

  f32x4 acc[2][4];
#pragma unroll
  for (int m = 0; m < 2; ++m)
#pragma unroll
    for (int nt = 0; nt < 4; ++nt)
      acc[m][nt] = (f32x4){0.f, 0.f, 0.f, 0.f};

  const float* xb = x + (size_t)b * CIN * HW;
  int ldsbase = t & ~63;          // wave-uniform LDS dest base

#define ISSUE_STAGE(CSTART, BUF)                                                \
  {                                                                             \
    const float* xsb_ = xb + (size_t)((CSTART) + (t & 3)) * HW + ob + (t >> 2); \
    float* wdst_ = &win[(BUF) * 2048 + ldsbase];                                \
    _Pragma("unroll")                                                           \
    for (int j_ = 0; j_ < 8; ++j_)                                              \
      __builtin_amdgcn_global_load_lds(                                         \
          (const __attribute__((address_space(1))) void*)(xsb_ + j_ * 64),      \
          (__attribute__((address_space(3))) void*)(wdst_ + j_ * 256),          \
          4, 0, 0);                                                             \
  }

// pack S as round-to-nearest bf16 pairs, single flavor; taps from wcur
#define GATHER(MW, MI, FASTE, ROW)                                              \
  {                                                                             \
    float s0_, s1_, s2_, s3_;                                                   \
    if (FASTE) {                                                                \
      float4 T0 = *(const float4*)&wcur[(MI.x - ob) * 4];                       \
      float4 T1 = *(const float4*)&wcur[(MI.y - ob) * 4];                       \
      float4 T2 = *(const float4*)&wcur[(MI.z - ob) * 4];                       \
      float4 T3 = *(const float4*)&wcur[(MI.w - ob) * 4];                       \
      s0_ = MW.x * T0.x + MW.y * T1.x + MW.z * T2.x + MW.w * T3.x;              \
      s1_ = MW.x * T0.y + MW.y * T1.y + MW.z * T2.y + MW.w * T3.y;              \
      s2_ = MW.x * T0.z + MW.y * T1.z + MW.z * T2.z + MW.w * T3.z;              \
      s3_ = MW.x * T0.w + MW.y * T1.w + MW.z * T2.w + MW.w * T3.w;              \
    } else {                                                                    \
      const float* xc_ = xb + (size_t)c4 * HW;                                  \
      s0_ = MW.x * xc_[MI.x] + MW.y * xc_[MI.y] + MW.z * xc_[MI.z] + MW.w * xc_[MI.w]; \
      xc_ += HW;                                                                \
      s1_ = MW.x * xc_[MI.x] + MW.y * xc_[MI.y] + MW.z * xc_[MI.z] + MW.w * xc_[MI.w]; \
      xc_ += HW;                                                                \
      s2_ = MW.x * xc_[MI.x] + MW.y * xc_[MI.y] + MW.z * xc_[MI.z] + MW.w * xc_[MI.w]; \
      xc_ += HW;                                                                \
      s3_ = MW.x * xc_[MI.x] + MW.y * xc_[MI.y] + MW.z * xc_[MI.z] + MW.w * xc_[MI.w]; \
    }                                                                           \
    unsigned a0_ = __float_as_uint(s0_) + 0x8000u;                              \
    unsigned a1_ = __float_as_uint(s1_) + 0x8000u;                              \
    unsigned a2_ = __float_as_uint(s2_) + 0x8000u;                              \
    unsigned a3_ = __float_as_uint(s3_) + 0x8000u;                              \
    unsigned hiA_ = (a0_ >> 16) | (a1_ & 0xFFFF0000u);                          \
    unsigned hiB_ = (a2_ >> 16) | (a3_ & 0xFFFF0000u);                          \
    int cp0_ = 2 * step;                                                        \
    int quad_ = (((ROW) >> 2) + (cp0_ >> 2)) & 3;                               \
    int word_ = (ROW) * 16 + quad_ * 4 + (cp0_ & 3);                            \
    *(uint2*)&sbuf[word_] = make_uint2(hiA_, hiB_);                             \
  }

  // prologue: stage chunk 0, step 0 into win[0]
  ISSUE_STAGE(c0, 0)
  __syncthreads();

  const int NCHUNK = CPC / 32;
  for (int chunk = 0; chunk < NCHUNK; ++chunk) {
    int cbase = c0 + chunk * 32;
    for (int step = 0; step < 8; ++step) {
      int c4 = cbase + step * 4;
      // issue next stage into the other buffer (next step, or next chunk's step 0)
      if (step < 7) {
        ISSUE_STAGE(cbase + (step + 1) * 4, (step + 1) & 1)
      } else if (chunk + 1 < NCHUNK) {
        ISSUE_STAGE(c0 + (chunk + 1) * 32, 0)
      }
      const float* wcur = &win[(step & 1) * 2048];
      GATHER(mw0, mi0, fast0, t)
      GATHER(mw1, mi1, fast1, 256 + t)
      if (hasC) GATHER(mw2, mi2, fast2, 512 + t)
      __syncthreads();   // completes issued loads + publishes sbuf writes
    }

    __builtin_amdgcn_s_setprio(1);
#pragma unroll
    for (int k = 0; k < 9; ++k) {
      short8v bh[4];
#pragma unroll
      for (int nt = 0; nt < 4; ++nt) {
        int row = k * 64 + nt * 16 + lrow;
        int quad = ((row >> 2) + lgrp) & 3;
        bh[nt] = *(const short8v*)&sbuf[row * 16 + quad * 4];
      }
#pragma unroll
      for (int m = 0; m < 2; ++m) {
        size_t widx = (((size_t)k * 32 + (cbase >> 3) + lgrp) * 128 + (wv * 32 + m * 16 + lrow)) * 8;
        short8v ah = *(const short8v*)(w_hi + widx);
        short8v al = *(const short8v*)(w_lo + widx);
#pragma unroll
        for (int nt = 0; nt < 4; ++nt) {
          acc[m][nt] = __builtin_amdgcn_mfma_f32_16x16x32_bf16(ah, bh[nt], acc[m][nt], 0, 0, 0);
          acc[m][nt] = __builtin_amdgcn_mfma_f32_16x16x32_bf16(al, bh[nt], acc[m][nt], 0, 0, 0);
        }
      }
    }
    __builtin_amdgcn_s_setprio(0);
    __syncthreads();
  }
#undef GATHER
#undef ISSUE_STAGE

#pragma unroll
  for (int m = 0; m < 2; ++m)
#pragma unroll
    for (int nt = 0; nt < 4; ++nt)
#pragma unroll
      for (int j = 0; j < 4; ++j) {
        int co = wv * 32 + m * 16 + lgrp * 4 + j;
        int p = h * 64 + nt * 16 + lrow;
        part[(((size_t)s2 * NB + b) * COUT + co) * HW + p] = acc[m][nt][j];
      }
}

// ---------------- fused reduce + bias + relu + 2x bilinear upsample (+XCD swizzle)
__global__ __launch_bounds__(256) void k_upred(
    const float* __restrict__ part, const float* __restrict__ bias_t,
    float* __restrict__ out)
{
  int bid = (blockIdx.x & 7) * 4096 + (blockIdx.x >> 3);  // bijective: 32768 = 8*4096
  int t = bid * 256 + threadIdx.x;
  if (t >= NB * COUT * 128 * 128) return;
  int j = t & 127;
  int i = (t >> 7) & 127;
  int bc = t >> 14;                 // b*COUT + co
  int co = bc & (COUT - 1);
  const float R = (float)(63.0 / 127.0);
  float pi = (float)i * R;
  float pj = (float)j * R;
  float i0f = floorf(pi), j0f = floorf(pj);
  int i0 = (int)i0f, j0 = (int)j0f;
  int i1 = min(i0 + 1, 63), j1 = min(j0 + 1, 63);
  float f = pi - i0f, g = pj - j0f;
  const float* p0 = part + (size_t)bc * HW;
  const float* p1 = part + (size_t)(CSPLIT - 1) * NB * COUT * HW + (size_t)bc * HW;
  float bv = bias_t[co];
  float a  = fmaxf(p0[i0 * 64 + j0] + p1[i0 * 64 + j0] + bv, 0.f);
  float bb = fmaxf(p0[i0 * 64 + j1] + p1[i0 * 64 + j1] + bv, 0.f);
  float cc = fmaxf(p0[i1 * 64 + j0] + p1[i1 * 64 + j0] + bv, 0.f);
  float dd = fmaxf(p0[i1 * 64 + j1] + p1[i1 * 64 + j1] + bv, 0.f);
  float t0 = a * (1.f - f) + cc * f;
  float t1 = bb * (1.f - f) + dd * f;
  out[t] = t0 * (1.f - g) + t1 * g;
}

extern "C" void kernel_launch(void* const* d_in, const int* in_sizes, int n_in,
                              void* d_out, int out_size, void* d_ws, size_t ws_size,
                              hipStream_t stream)
{
  const float* x     = (const float*)d_in[0];
  const float* w_off = (const float*)d_in[1];
  const float* b_off = (const float*)d_in[2];
  const float* w_dcn = (const float*)d_in[3];
  const float* b_dcn = (const float*)d_in[4];
  const float* gamma = (const float*)d_in[5];
  const float* beta  = (const float*)d_in[6];
  const float* rmean = (const float*)d_in[7];
  const float* rvar  = (const float*)d_in[8];
  float* out = (float*)d_out;

  char* ws = (char*)d_ws;
  size_t off = 0;
  auto alloc = [&](size_t bytes) {
    void* p = ws + off;
    off = (off + bytes + 255) & ~255UL;
    return p;
  };
  float*  om_part = (float*) alloc(sizeof(float)  * OCSPLIT * NB * 27 * HW);
  float4* md_w    = (float4*)alloc(sizeof(float4) * NB * 9 * HW);
  int4*   md_i    = (int4*)  alloc(sizeof(int4)   * NB * 9 * HW);
  unsigned short* w_hi = (unsigned short*)alloc(sizeof(unsigned short) * 9 * CIN * COUT);
  unsigned short* w_lo = (unsigned short*)alloc(sizeof(unsigned short) * 9 * CIN * COUT);
  unsigned short* wo_hi = (unsigned short*)alloc(sizeof(unsigned short) * 9 * 32 * 32 * 8);
  unsigned short* wo_lo = (unsigned short*)alloc(sizeof(unsigned short) * 9 * 32 * 32 * 8);
  float*  bias_t  = (float*) alloc(sizeof(float)  * COUT);
  float*  part    = (float*) alloc(sizeof(float)  * CSPLIT * NB * COUT * HW);
  (void)ws_size; (void)in_sizes; (void)n_in; (void)out_size;

  k_prep_w<<<(CIN * COUT * 9 + 255) / 256, 256, 0, stream>>>(
      w_dcn, b_dcn, gamma, beta, rmean, rvar, w_hi, w_lo, bias_t);
  k_prep_wo<<<(9 * 32 * 32 * 8 + 255) / 256, 256, 0, stream>>>(w_off, wo_hi, wo_lo);
  k_off_mfma<<<NB * 64 * 4, 256, 0, stream>>>(x, wo_hi, wo_lo, om_part);
  k_prep_md<<<(NB * 9 * HW + 255) / 256, 256, 0, stream>>>(om_part, b_off, md_w, md_i);
  k_dcn<<<CSPLIT * NB * 64, 256, 0, stream>>>(x, w_hi, w_lo, md_w, md_i, part);
  k_upred<<<(NB * COUT * 128 * 128 + 255) / 256, 256, 0, stream>>>(part, bias_t, out);
}

// Round 27
// 109.540 us; speedup vs baseline: 1.0583x; 1.0583x over previous
//
#include <hip/hip_runtime.h>
#include <math.h>

#define CIN  256
#define COUT 128
#define HW   4096
#define NB   4
#define OCSPLIT 4
#define CSPLIT  4
#define CPC  (CIN / CSPLIT)      // 64 channels per k_dcn block (2 chunks of 32)
#define SFLAV (576 * 16)         // u32 words in k_dcn sbuf (hi flavor only)

typedef short short8v __attribute__((ext_vector_type(8)));
typedef float f32x4  __attribute__((ext_vector_type(4)));

// ---------------- weight prep (DCN): bf16 hi/lo split, fragment-ready layout
__global__ __launch_bounds__(256) void k_prep_w(
    const float* __restrict__ w_dcn, const float* __restrict__ b_dcn,
    const float* __restrict__ gamma, const float* __restrict__ beta,
    const float* __restrict__ rmean, const float* __restrict__ rvar,
    unsigned short* __restrict__ w_hi, unsigned short* __restrict__ w_lo,
    float* __restrict__ bias_t)
{
  int t = blockIdx.x * 256 + threadIdx.x;
  if (t < COUT) {
    float sc = gamma[t] * rsqrtf(rvar[t] + 1e-5f);
    bias_t[t] = b_dcn[t] * sc + beta[t] - rmean[t] * sc;
  }
  if (t >= CIN * COUT * 9) return;
  int k = t % 9;
  int q = t / 9;
  int co = q % COUT;
  int c  = q / COUT;
  float sc = gamma[co] * rsqrtf(rvar[co] + 1e-5f);
  float w = w_dcn[((size_t)co * CIN + c) * 9 + k] * sc;
  unsigned int wb = __float_as_uint(w);
  unsigned short hi = (unsigned short)(wb >> 16);
  float lof = w - __uint_as_float(wb & 0xFFFF0000u);
  unsigned short lo = (unsigned short)(__float_as_uint(lof) >> 16);
  size_t idx = (((size_t)k * 32 + (c >> 3)) * 128 + co) * 8 + (c & 7);
  w_hi[idx] = hi;
  w_lo[idx] = lo;
}

// ---------------- weight prep (offset conv): [k][cq][co32][8ch], co>=27 zero
__global__ __launch_bounds__(256) void k_prep_wo(
    const float* __restrict__ w_off,
    unsigned short* __restrict__ wo_hi, unsigned short* __restrict__ wo_lo)
{
  int t = blockIdx.x * 256 + threadIdx.x;
  if (t >= 9 * 32 * 32 * 8) return;
  int ce = t & 7;
  int co = (t >> 3) & 31;
  int cq = (t >> 8) & 31;
  int k  = t >> 13;
  int c = cq * 8 + ce;
  float w = (co < 27) ? w_off[((size_t)co * CIN + c) * 9 + k] : 0.f;
  unsigned int wb = __float_as_uint(w);
  unsigned short hi = (unsigned short)(wb >> 16);
  float lof = w - __uint_as_float(wb & 0xFFFF0000u);
  unsigned short lo = (unsigned short)(__float_as_uint(lof) >> 16);
  wo_hi[t] = hi;
  wo_lo[t] = lo;
}

// ---------------- offset conv via MFMA (R20) + XCD swizzle (grid 1024 = 8 x 128)
__global__ __launch_bounds__(256, 4) void k_off_mfma(
    const float* __restrict__ x,
    const unsigned short* __restrict__ wo_hi, const unsigned short* __restrict__ wo_lo,
    float* __restrict__ om_part)
{
  int blk = (blockIdx.x & 7) * 128 + (blockIdx.x >> 3);  // bijective: 1024 = 8*128
  int split = blk & 3;
  int bh = blk >> 2;
  int b = bh >> 6, h = bh & 63;
  int t = threadIdx.x;
  int lane = t & 63;
  int wv = t >> 6;
  int lrow = lane & 15, lgrp = lane >> 4;

  __shared__ __align__(16) unsigned int win_hi[3 * 66 * 20];
  __shared__ __align__(16) unsigned int win_lo[3 * 66 * 20];

  f32x4 acc[2];
  acc[0] = (f32x4){0.f, 0.f, 0.f, 0.f};
  acc[1] = (f32x4){0.f, 0.f, 0.f, 0.f};

  const float* xb = x + (size_t)b * CIN * HW;

  for (int chunk = 0; chunk < 2; ++chunk) {
    int cbase = split * 64 + chunk * 32;
    for (int i = t; i < 3168; i += 256) {
      int cp = i / 198;
      int s  = i - cp * 198;
      int r  = s / 66;
      int colp = s - r * 66;
      int row = h + r - 1;
      int col = colp - 1;
      bool v = ((unsigned)row < 64u) && ((unsigned)col < 64u);
      int ch = cbase + 2 * cp;
      float f0 = 0.f, f1 = 0.f;
      if (v) {
        const float* xp = xb + ((size_t)ch * 64 + row) * 64 + col;
        f0 = xp[0];
        f1 = xp[HW];
      }
      unsigned a0 = __float_as_uint(f0), a1 = __float_as_uint(f1);
      unsigned hi = (a0 >> 16) | (a1 & 0xFFFF0000u);
      float l0 = f0 - __uint_as_float(a0 & 0xFFFF0000u);
      float l1 = f1 - __uint_as_float(a1 & 0xFFFF0000u);
      unsigned lo = (__float_as_uint(l0) >> 16) | (__float_as_uint(l1) & 0xFFFF0000u);
      win_hi[s * 20 + cp] = hi;
      win_lo[s * 20 + cp] = lo;
    }
    __syncthreads();

    int pos = wv * 16 + lrow;
#pragma unroll
    for (int k = 0; k < 9; ++k) {
      int ky = k / 3 - 1, kx = k % 3 - 1;
      int slot = (ky + 1) * 66 + pos + kx + 1;
      const unsigned int* ph = &win_hi[slot * 20 + lgrp * 4];
      const unsigned int* pl = &win_lo[slot * 20 + lgrp * 4];
      short8v bh = *(const short8v*)ph;
      short8v bl = *(const short8v*)pl;
#pragma unroll
      for (int m = 0; m < 2; ++m) {
        size_t widx = (((size_t)k * 32 + (cbase >> 3) + lgrp) * 32 + m * 16 + lrow) * 8;
        short8v ah = *(const short8v*)(wo_hi + widx);
        short8v al = *(const short8v*)(wo_lo + widx);
        acc[m] = __builtin_amdgcn_mfma_f32_16x16x32_bf16(ah, bh, acc[m], 0, 0, 0);
        acc[m] = __builtin_amdgcn_mfma_f32_16x16x32_bf16(ah, bl, acc[m], 0, 0, 0);
        acc[m] = __builtin_amdgcn_mfma_f32_16x16x32_bf16(al, bh, acc[m], 0, 0, 0);
      }
    }
    __syncthreads();
  }

  int pos = wv * 16 + lrow;
#pragma unroll
  for (int m = 0; m < 2; ++m)
#pragma unroll
    for (int j = 0; j < 4; ++j) {
      int co = m * 16 + lgrp * 4 + j;
      if (co < 27)
        om_part[(((size_t)split * NB + b) * 27 + co) * HW + h * 64 + pos] = acc[m][j];
    }
}

// ---------------- sampling metadata (sums OCSPLIT=4 partials)
__global__ __launch_bounds__(256) void k_prep_md(
    const float* __restrict__ om_part, const float* __restrict__ b_off,
    float4* __restrict__ md_w, int4* __restrict__ md_i)
{
  int t = blockIdx.x * 256 + threadIdx.x;
  if (t >= NB * 9 * HW) return;
  int hw = t & 4095;
  int bk = t >> 12;
  int k = bk % 9;
  int b = bk / 9;
  int h = hw >> 6, w = hw & 63;

  float dy = b_off[2 * k], dx = b_off[2 * k + 1], mr = b_off[18 + k];
#pragma unroll
  for (int s = 0; s < OCSPLIT; ++s) {
    size_t o = ((size_t)s * NB + b) * 27 * HW + hw;
    dy += om_part[o + (size_t)(2 * k) * HW];
    dx += om_part[o + (size_t)(2 * k + 1) * HW];
    mr += om_part[o + (size_t)(18 + k) * HW];
  }
  float m = 1.0f / (1.0f + expf(-mr));

  int ky = k / 3 - 1, kx = k % 3 - 1;
  float py = dy + (float)h + (float)ky;
  float px = dx + (float)w + (float)kx;
  float y0f = floorf(py), x0f = floorf(px);
  float fy = py - y0f, fx = px - x0f;
  int y0 = (int)y0f, x0 = (int)x0f;
  int y1 = y0 + 1, x1 = x0 + 1;

  bool vy0 = (y0 >= 0) & (y0 < 64), vy1 = (y1 >= 0) & (y1 < 64);
  bool vx0 = (x0 >= 0) & (x0 < 64), vx1 = (x1 >= 0) & (x1 < 64);
  int cy0 = min(max(y0, 0), 63), cy1 = min(max(y1, 0), 63);
  int cx0 = min(max(x0, 0), 63), cx1 = min(max(x1, 0), 63);

  float4 wv;
  wv.x = (vy0 && vx0) ? (1.f - fy) * (1.f - fx) * m : 0.f;
  wv.y = (vy0 && vx1) ? (1.f - fy) * fx * m : 0.f;
  wv.z = (vy1 && vx0) ? fy * (1.f - fx) * m : 0.f;
  wv.w = (vy1 && vx1) ? fy * fx * m : 0.f;
  int4 iv;
  iv.x = cy0 * 64 + cx0;
  iv.y = cy0 * 64 + cx1;
  iv.z = cy1 * 64 + cx0;
  iv.w = cy1 * 64 + cx1;
  md_w[t] = wv;
  md_i[t] = iv;
}

// ---------------- DCN: R25 structure, CSPLIT=4 (64 ch/block, 3 blocks/CU resident)
// grid = 1024 = 8 XCDs x 128; swizzle bijective; s2 = blk>>8 in [0,4)
__global__ __launch_bounds__(256, 3) void k_dcn(
    const float* __restrict__ x,
    const unsigned short* __restrict__ w_hi, const unsigned short* __restrict__ w_lo,
    const float4* __restrict__ md_w, const int4* __restrict__ md_i,
    float* __restrict__ part)
{
  int blk = (blockIdx.x & 7) * 128 + (blockIdx.x >> 3);  // bijective: 1024 = 8*128
  int h = blk & 63;
  int b = (blk >> 6) & (NB - 1);
  int s2 = blk >> 8;
  int c0 = s2 * CPC;
  int t = threadIdx.x;
  int lane = t & 63;
  int wv = t >> 6;
  int lrow = lane & 15, lgrp = lane >> 4;

  __shared__ __align__(16) unsigned int sbuf[SFLAV];      // 36864 B (hi only)
  __shared__ __align__(16) float win[8 * 64 * 4];         // 8192 B, channel-last

  int W0 = min(max(h - 3, 0), 56);
  int ob = W0 * 64;

  int k0 = t >> 6;
  size_t mdbase = (size_t)b * 9 * HW;
  size_t mdp = mdbase + (size_t)h * 64 + (t & 63);
  float4 mw0 = md_w[mdp + (size_t)k0 * HW];
  int4  mi0 = md_i[mdp + (size_t)k0 * HW];
  float4 mw1 = md_w[mdp + (size_t)(k0 + 4) * HW];
  int4  mi1 = md_i[mdp + (size_t)(k0 + 4) * HW];
  bool hasC = (t < 64);
  float4 mw2 = make_float4(0.f, 0.f, 0.f, 0.f);
  int4  mi2 = make_int4(0, 0, 0, 0);
  if (hasC) {
    mw2 = md_w[mdp + (size_t)8 * HW];
    mi2 = md_i[mdp + (size_t)8 * HW];
  }
  int fast0 = __all(((unsigned)(mi0.x - ob) < 512u) && ((unsigned)(mi0.z - ob) < 512u));
  int fast1 = __all(((unsigned)(mi1.x - ob) < 512u) && ((unsigned)(mi1.z - ob) < 512u));
  int fast2 = __all(((unsigned)(mi2.x - ob) < 512u) && ((unsigned)(mi2.z - ob) < 512u));

  f32x4 acc[2][4];
#pragma unroll
  for (int m = 0; m < 2; ++m)
#pragma unroll
    for (int nt = 0; nt < 4; ++nt)
      acc[m][nt] = (f32x4){0.f, 0.f, 0.f, 0.f};

  const float* xb = x + (size_t)b * CIN * HW;

// pack S as round-to-nearest bf16 pairs, single flavor
#define GATHER(MW, MI, FASTE, ROW)                                              \
  {                                                                             \
    float s0_, s1_, s2_, s3_;                                                   \
    if (FASTE) {                                                                \
      float4 T0 = *(const float4*)&win[(MI.x - ob) * 4];                        \
      float4 T1 = *(const float4*)&win[(MI.y - ob) * 4];                        \
      float4 T2 = *(const float4*)&win[(MI.z - ob) * 4];                        \
      float4 T3 = *(const float4*)&win[(MI.w - ob) * 4];                        \
      s0_ = MW.x * T0.x + MW.y * T1.x + MW.z * T2.x + MW.w * T3.x;              \
      s1_ = MW.x * T0.y + MW.y * T1.y + MW.z * T2.y + MW.w * T3.y;              \
      s2_ = MW.x * T0.z + MW.y * T1.z + MW.z * T2.z + MW.w * T3.z;              \
      s3_ = MW.x * T0.w + MW.y * T1.w + MW.z * T2.w + MW.w * T3.w;              \
    } else {                                                                    \
      const float* xc_ = xb + (size_t)c4 * HW;                                  \
      s0_ = MW.x * xc_[MI.x] + MW.y * xc_[MI.y] + MW.z * xc_[MI.z] + MW.w * xc_[MI.w]; \
      xc_ += HW;                                                                \
      s1_ = MW.x * xc_[MI.x] + MW.y * xc_[MI.y] + MW.z * xc_[MI.z] + MW.w * xc_[MI.w]; \
      xc_ += HW;                                                                \
      s2_ = MW.x * xc_[MI.x] + MW.y * xc_[MI.y] + MW.z * xc_[MI.z] + MW.w * xc_[MI.w]; \
      xc_ += HW;                                                                \
      s3_ = MW.x * xc_[MI.x] + MW.y * xc_[MI.y] + MW.z * xc_[MI.z] + MW.w * xc_[MI.w]; \
    }                                                                           \
    unsigned a0_ = __float_as_uint(s0_) + 0x8000u;                              \
    unsigned a1_ = __float_as_uint(s1_) + 0x8000u;                              \
    unsigned a2_ = __float_as_uint(s2_) + 0x8000u;                              \
    unsigned a3_ = __float_as_uint(s3_) + 0x8000u;                              \
    unsigned hiA_ = (a0_ >> 16) | (a1_ & 0xFFFF0000u);                          \
    unsigned hiB_ = (a2_ >> 16) | (a3_ & 0xFFFF0000u);                          \
    int cp0_ = 2 * step;                                                        \
    int quad_ = (((ROW) >> 2) + (cp0_ >> 2)) & 3;                               \
    int word_ = (ROW) * 16 + quad_ * 4 + (cp0_ & 3);                            \
    *(uint2*)&sbuf[word_] = make_uint2(hiA_, hiB_);                             \
  }

  for (int chunk = 0; chunk < CPC / 32; ++chunk) {
    int cbase = c0 + chunk * 32;
    for (int step = 0; step < 8; ++step) {
      int c4 = cbase + step * 4;
      {
        const float* xsb = xb + (size_t)(c4 + (t & 3)) * HW + ob + (t >> 2);
        int ldsbase = t & ~63;    // wave-uniform
#pragma unroll
        for (int j = 0; j < 8; ++j)
          __builtin_amdgcn_global_load_lds(
              (const __attribute__((address_space(1))) void*)(xsb + j * 64),
              (__attribute__((address_space(3))) void*)&win[j * 256 + ldsbase],
              4, 0, 0);
      }
      __syncthreads();
      GATHER(mw0, mi0, fast0, t)
      GATHER(mw1, mi1, fast1, 256 + t)
      if (hasC) GATHER(mw2, mi2, fast2, 512 + t)
      __syncthreads();
    }

    __builtin_amdgcn_s_setprio(1);
#pragma unroll
    for (int k = 0; k < 9; ++k) {
      short8v bh[4];
#pragma unroll
      for (int nt = 0; nt < 4; ++nt) {
        int row = k * 64 + nt * 16 + lrow;
        int quad = ((row >> 2) + lgrp) & 3;
        bh[nt] = *(const short8v*)&sbuf[row * 16 + quad * 4];
      }
#pragma unroll
      for (int m = 0; m < 2; ++m) {
        size_t widx = (((size_t)k * 32 + (cbase >> 3) + lgrp) * 128 + (wv * 32 + m * 16 + lrow)) * 8;
        short8v ah = *(const short8v*)(w_hi + widx);
        short8v al = *(const short8v*)(w_lo + widx);
#pragma unroll
        for (int nt = 0; nt < 4; ++nt) {
          acc[m][nt] = __builtin_amdgcn_mfma_f32_16x16x32_bf16(ah, bh[nt], acc[m][nt], 0, 0, 0);
          acc[m][nt] = __builtin_amdgcn_mfma_f32_16x16x32_bf16(al, bh[nt], acc[m][nt], 0, 0, 0);
        }
      }
    }
    __builtin_amdgcn_s_setprio(0);
    __syncthreads();
  }
#undef GATHER

#pragma unroll
  for (int m = 0; m < 2; ++m)
#pragma unroll
    for (int nt = 0; nt < 4; ++nt)
#pragma unroll
      for (int j = 0; j < 4; ++j) {
        int co = wv * 32 + m * 16 + lgrp * 4 + j;
        int p = h * 64 + nt * 16 + lrow;
        part[(((size_t)s2 * NB + b) * COUT + co) * HW + p] = acc[m][nt][j];
      }
}

// ---------------- fused reduce(4) + bias + relu + 2x bilinear upsample (+XCD swizzle)
__global__ __launch_bounds__(256) void k_upred(
    const float* __restrict__ part, const float* __restrict__ bias_t,
    float* __restrict__ out)
{
  int bid = (blockIdx.x & 7) * 4096 + (blockIdx.x >> 3);  // bijective: 32768 = 8*4096
  int t = bid * 256 + threadIdx.x;
  if (t >= NB * COUT * 128 * 128) return;
  int j = t & 127;
  int i = (t >> 7) & 127;
  int bc = t >> 14;                 // b*COUT + co
  int co = bc & (COUT - 1);
  const float R = (float)(63.0 / 127.0);
  float pi = (float)i * R;
  float pj = (float)j * R;
  float i0f = floorf(pi), j0f = floorf(pj);
  int i0 = (int)i0f, j0 = (int)j0f;
  int i1 = min(i0 + 1, 63), j1 = min(j0 + 1, 63);
  float f = pi - i0f, g = pj - j0f;
  int e00 = i0 * 64 + j0, e01 = i0 * 64 + j1;
  int e10 = i1 * 64 + j0, e11 = i1 * 64 + j1;
  float a = 0.f, bb = 0.f, cc = 0.f, dd = 0.f;
#pragma unroll
  for (int s = 0; s < CSPLIT; ++s) {
    const float* p0 = part + (size_t)s * (NB * COUT * HW) + (size_t)bc * HW;
    a  += p0[e00];
    bb += p0[e01];
    cc += p0[e10];
    dd += p0[e11];
  }
  float bv = bias_t[co];
  a  = fmaxf(a + bv, 0.f);
  bb = fmaxf(bb + bv, 0.f);
  cc = fmaxf(cc + bv, 0.f);
  dd = fmaxf(dd + bv, 0.f);
  float t0 = a * (1.f - f) + cc * f;
  float t1 = bb * (1.f - f) + dd * f;
  out[t] = t0 * (1.f - g) + t1 * g;
}

extern "C" void kernel_launch(void* const* d_in, const int* in_sizes, int n_in,
                              void* d_out, int out_size, void* d_ws, size_t ws_size,
                              hipStream_t stream)
{
  const float* x     = (const float*)d_in[0];
  const float* w_off = (const float*)d_in[1];
  const float* b_off = (const float*)d_in[2];
  const float* w_dcn = (const float*)d_in[3];
  const float* b_dcn = (const float*)d_in[4];
  const float* gamma = (const float*)d_in[5];
  const float* beta  = (const float*)d_in[6];
  const float* rmean = (const float*)d_in[7];
  const float* rvar  = (const float*)d_in[8];
  float* out = (float*)d_out;

  char* ws = (char*)d_ws;
  size_t off = 0;
  auto alloc = [&](size_t bytes) {
    void* p = ws + off;
    off = (off + bytes + 255) & ~255UL;
    return p;
  };
  float*  om_part = (float*) alloc(sizeof(float)  * OCSPLIT * NB * 27 * HW);
  float4* md_w    = (float4*)alloc(sizeof(float4) * NB * 9 * HW);
  int4*   md_i    = (int4*)  alloc(sizeof(int4)   * NB * 9 * HW);
  unsigned short* w_hi = (unsigned short*)alloc(sizeof(unsigned short) * 9 * CIN * COUT);
  unsigned short* w_lo = (unsigned short*)alloc(sizeof(unsigned short) * 9 * CIN * COUT);
  unsigned short* wo_hi = (unsigned short*)alloc(sizeof(unsigned short) * 9 * 32 * 32 * 8);
  unsigned short* wo_lo = (unsigned short*)alloc(sizeof(unsigned short) * 9 * 32 * 32 * 8);
  float*  bias_t  = (float*) alloc(sizeof(float)  * COUT);
  float*  part    = (float*) alloc(sizeof(float)  * CSPLIT * NB * COUT * HW);
  (void)ws_size; (void)in_sizes; (void)n_in; (void)out_size;

  k_prep_w<<<(CIN * COUT * 9 + 255) / 256, 256, 0, stream>>>(
      w_dcn, b_dcn, gamma, beta, rmean, rvar, w_hi, w_lo, bias_t);
  k_prep_wo<<<(9 * 32 * 32 * 8 + 255) / 256, 256, 0, stream>>>(w_off, wo_hi, wo_lo);
  k_off_mfma<<<NB * 64 * 4, 256, 0, stream>>>(x, wo_hi, wo_lo, om_part);
  k_prep_md<<<(NB * 9 * HW + 255) / 256, 256, 0, stream>>>(om_part, b_off, md_w, md_i);
  k_dcn<<<CSPLIT * NB * 64, 256, 0, stream>>>(x, w_hi, w_lo, md_w, md_i, part);
  k_upred<<<(NB * COUT * 128 * 128 + 255) / 256, 256, 0, stream>>>(part, bias_t, out);
}

// Round 28
// 104.645 us; speedup vs baseline: 1.1078x; 1.0468x over previous
//
#include <hip/hip_runtime.h>
#include <math.h>

#define CIN  256
#define COUT 128
#define HW   4096
#define NB   4
#define OCSPLIT 4
#define CSPLIT  2
#define CPC  (CIN / CSPLIT)      // 128 channels per k_dcn block (4 chunks of 32)
#define SFLAV (576 * 16)         // u32 words in k_dcn sbuf (hi flavor only)

typedef short short8v __attribute__((ext_vector_type(8)));
typedef float f32x4  __attribute__((ext_vector_type(4)));

// ---------------- weight prep (DCN): bf16 hi/lo split, fragment-ready layout
__global__ __launch_bounds__(256) void k_prep_w(
    const float* __restrict__ w_dcn, const float* __restrict__ b_dcn,
    const float* __restrict__ gamma, const float* __restrict__ beta,
    const float* __restrict__ rmean, const float* __restrict__ rvar,
    unsigned short* __restrict__ w_hi, unsigned short* __restrict__ w_lo,
    float* __restrict__ bias_t)
{
  int t = blockIdx.x * 256 + threadIdx.x;
  if (t < COUT) {
    float sc = gamma[t] * rsqrtf(rvar[t] + 1e-5f);
    bias_t[t] = b_dcn[t] * sc + beta[t] - rmean[t] * sc;
  }
  if (t >= CIN * COUT * 9) return;
  int k = t % 9;
  int q = t / 9;
  int co = q % COUT;
  int c  = q / COUT;
  float sc = gamma[co] * rsqrtf(rvar[co] + 1e-5f);
  float w = w_dcn[((size_t)co * CIN + c) * 9 + k] * sc;
  unsigned int wb = __float_as_uint(w);
  unsigned short hi = (unsigned short)(wb >> 16);
  float lof = w - __uint_as_float(wb & 0xFFFF0000u);
  unsigned short lo = (unsigned short)(__float_as_uint(lof) >> 16);
  size_t idx = (((size_t)k * 32 + (c >> 3)) * 128 + co) * 8 + (c & 7);
  w_hi[idx] = hi;
  w_lo[idx] = lo;
}

// ---------------- weight prep (offset conv): [k][cq][co32][8ch], co>=27 zero
__global__ __launch_bounds__(256) void k_prep_wo(
    const float* __restrict__ w_off,
    unsigned short* __restrict__ wo_hi, unsigned short* __restrict__ wo_lo)
{
  int t = blockIdx.x * 256 + threadIdx.x;
  if (t >= 9 * 32 * 32 * 8) return;
  int ce = t & 7;
  int co = (t >> 3) & 31;
  int cq = (t >> 8) & 31;
  int k  = t >> 13;
  int c = cq * 8 + ce;
  float w = (co < 27) ? w_off[((size_t)co * CIN + c) * 9 + k] : 0.f;
  unsigned int wb = __float_as_uint(w);
  unsigned short hi = (unsigned short)(wb >> 16);
  float lof = w - __uint_as_float(wb & 0xFFFF0000u);
  unsigned short lo = (unsigned short)(__float_as_uint(lof) >> 16);
  wo_hi[t] = hi;
  wo_lo[t] = lo;
}

// ---------------- offset conv via MFMA (R20) + XCD swizzle (grid 1024 = 8 x 128)
__global__ __launch_bounds__(256, 4) void k_off_mfma(
    const float* __restrict__ x,
    const unsigned short* __restrict__ wo_hi, const unsigned short* __restrict__ wo_lo,
    float* __restrict__ om_part)
{
  int blk = (blockIdx.x & 7) * 128 + (blockIdx.x >> 3);  // bijective: 1024 = 8*128
  int split = blk & 3;
  int bh = blk >> 2;
  int b = bh >> 6, h = bh & 63;
  int t = threadIdx.x;
  int lane = t & 63;
  int wv = t >> 6;
  int lrow = lane & 15, lgrp = lane >> 4;

  __shared__ __align__(16) unsigned int win_hi[3 * 66 * 20];
  __shared__ __align__(16) unsigned int win_lo[3 * 66 * 20];

  f32x4 acc[2];
  acc[0] = (f32x4){0.f, 0.f, 0.f, 0.f};
  acc[1] = (f32x4){0.f, 0.f, 0.f, 0.f};

  const float* xb = x + (size_t)b * CIN * HW;

  for (int chunk = 0; chunk < 2; ++chunk) {
    int cbase = split * 64 + chunk * 32;
    for (int i = t; i < 3168; i += 256) {
      int cp = i / 198;
      int s  = i - cp * 198;
      int r  = s / 66;
      int colp = s - r * 66;
      int row = h + r - 1;
      int col = colp - 1;
      bool v = ((unsigned)row < 64u) && ((unsigned)col < 64u);
      int ch = cbase + 2 * cp;
      float f0 = 0.f, f1 = 0.f;
      if (v) {
        const float* xp = xb + ((size_t)ch * 64 + row) * 64 + col;
        f0 = xp[0];
        f1 = xp[HW];
      }
      unsigned a0 = __float_as_uint(f0), a1 = __float_as_uint(f1);
      unsigned hi = (a0 >> 16) | (a1 & 0xFFFF0000u);
      float l0 = f0 - __uint_as_float(a0 & 0xFFFF0000u);
      float l1 = f1 - __uint_as_float(a1 & 0xFFFF0000u);
      unsigned lo = (__float_as_uint(l0) >> 16) | (__float_as_uint(l1) & 0xFFFF0000u);
      win_hi[s * 20 + cp] = hi;
      win_lo[s * 20 + cp] = lo;
    }
    __syncthreads();

    int pos = wv * 16 + lrow;
#pragma unroll
    for (int k = 0; k < 9; ++k) {
      int ky = k / 3 - 1, kx = k % 3 - 1;
      int slot = (ky + 1) * 66 + pos + kx + 1;
      const unsigned int* ph = &win_hi[slot * 20 + lgrp * 4];
      const unsigned int* pl = &win_lo[slot * 20 + lgrp * 4];
      short8v bh = *(const short8v*)ph;
      short8v bl = *(const short8v*)pl;
#pragma unroll
      for (int m = 0; m < 2; ++m) {
        size_t widx = (((size_t)k * 32 + (cbase >> 3) + lgrp) * 32 + m * 16 + lrow) * 8;
        short8v ah = *(const short8v*)(wo_hi + widx);
        short8v al = *(const short8v*)(wo_lo + widx);
        acc[m] = __builtin_amdgcn_mfma_f32_16x16x32_bf16(ah, bh, acc[m], 0, 0, 0);
        acc[m] = __builtin_amdgcn_mfma_f32_16x16x32_bf16(ah, bl, acc[m], 0, 0, 0);
        acc[m] = __builtin_amdgcn_mfma_f32_16x16x32_bf16(al, bh, acc[m], 0, 0, 0);
      }
    }
    __syncthreads();
  }

  int pos = wv * 16 + lrow;
#pragma unroll
  for (int m = 0; m < 2; ++m)
#pragma unroll
    for (int j = 0; j < 4; ++j) {
      int co = m * 16 + lgrp * 4 + j;
      if (co < 27)
        om_part[(((size_t)split * NB + b) * 27 + co) * HW + h * 64 + pos] = acc[m][j];
    }
}

// ---------------- sampling metadata (sums OCSPLIT=4 partials)
__global__ __launch_bounds__(256) void k_prep_md(
    const float* __restrict__ om_part, const float* __restrict__ b_off,
    float4* __restrict__ md_w, int4* __restrict__ md_i)
{
  int t = blockIdx.x * 256 + threadIdx.x;
  if (t >= NB * 9 * HW) return;
  int hw = t & 4095;
  int bk = t >> 12;
  int k = bk % 9;
  int b = bk / 9;
  int h = hw >> 6, w = hw & 63;

  float dy = b_off[2 * k], dx = b_off[2 * k + 1], mr = b_off[18 + k];
#pragma unroll
  for (int s = 0; s < OCSPLIT; ++s) {
    size_t o = ((size_t)s * NB + b) * 27 * HW + hw;
    dy += om_part[o + (size_t)(2 * k) * HW];
    dx += om_part[o + (size_t)(2 * k + 1) * HW];
    mr += om_part[o + (size_t)(18 + k) * HW];
  }
  float m = 1.0f / (1.0f + expf(-mr));

  int ky = k / 3 - 1, kx = k % 3 - 1;
  float py = dy + (float)h + (float)ky;
  float px = dx + (float)w + (float)kx;
  float y0f = floorf(py), x0f = floorf(px);
  float fy = py - y0f, fx = px - x0f;
  int y0 = (int)y0f, x0 = (int)x0f;
  int y1 = y0 + 1, x1 = x0 + 1;

  bool vy0 = (y0 >= 0) & (y0 < 64), vy1 = (y1 >= 0) & (y1 < 64);
  bool vx0 = (x0 >= 0) & (x0 < 64), vx1 = (x1 >= 0) & (x1 < 64);
  int cy0 = min(max(y0, 0), 63), cy1 = min(max(y1, 0), 63);
  int cx0 = min(max(x0, 0), 63), cx1 = min(max(x1, 0), 63);

  float4 wv;
  wv.x = (vy0 && vx0) ? (1.f - fy) * (1.f - fx) * m : 0.f;
  wv.y = (vy0 && vx1) ? (1.f - fy) * fx * m : 0.f;
  wv.z = (vy1 && vx0) ? fy * (1.f - fx) * m : 0.f;
  wv.w = (vy1 && vx1) ? fy * fx * m : 0.f;
  int4 iv;
  iv.x = cy0 * 64 + cx0;
  iv.y = cy0 * 64 + cx1;
  iv.z = cy1 * 64 + cx0;
  iv.w = cy1 * 64 + cx1;
  md_w[t] = wv;
  md_i[t] = iv;
}

// ---------------- DCN: P=64 channel-last LDS window + MFMA (R25, validated best)
// S rounded bf16 (2-term MFMA), XCD swizzle, async staging. LDS 45056 B.
__global__ __launch_bounds__(256, 3) void k_dcn(
    const float* __restrict__ x,
    const unsigned short* __restrict__ w_hi, const unsigned short* __restrict__ w_lo,
    const float4* __restrict__ md_w, const int4* __restrict__ md_i,
    float* __restrict__ part)
{
  int blk = (blockIdx.x & 7) * 64 + (blockIdx.x >> 3);  // bijective: 512 = 8*64
  int h = blk & 63;
  int b = (blk >> 6) & (NB - 1);
  int s2 = blk >> 8;
  int c0 = s2 * CPC;
  int t = threadIdx.x;
  int lane = t & 63;
  int wv = t >> 6;
  int lrow = lane & 15, lgrp = lane >> 4;

  __shared__ __align__(16) unsigned int sbuf[SFLAV];      // 36864 B (hi only)
  __shared__ __align__(16) float win[8 * 64 * 4];         // 8192 B, channel-last

  int W0 = min(max(h - 3, 0), 56);
  int ob = W0 * 64;

  int k0 = t >> 6;
  size_t mdbase = (size_t)b * 9 * HW;
  size_t mdp = mdbase + (size_t)h * 64 + (t & 63);
  float4 mw0 = md_w[mdp + (size_t)k0 * HW];
  int4  mi0 = md_i[mdp + (size_t)k0 * HW];
  float4 mw1 = md_w[mdp + (size_t)(k0 + 4) * HW];
  int4  mi1 = md_i[mdp + (size_t)(k0 + 4) * HW];
  bool hasC = (t < 64);
  float4 mw2 = make_float4(0.f, 0.f, 0.f, 0.f);
  int4  mi2 = make_int4(0, 0, 0, 0);
  if (hasC) {
    mw2 = md_w[mdp + (size_t)8 * HW];
    mi2 = md_i[mdp + (size_t)8 * HW];
  }
  int fast0 = __all(((unsigned)(mi0.x - ob) < 512u) && ((unsigned)(mi0.z - ob) < 512u));
  int fast1 = __all(((unsigned)(mi1.x - ob) < 512u) && ((unsigned)(mi1.z - ob) < 512u));
  int fast2 = __all(((unsigned)(mi2.x - ob) < 512u) && ((unsigned)(mi2.z - ob) < 512u));

  f32x4 acc[2][4];
#pragma unroll
  for (int m = 0; m < 2; ++m)
#pragma unroll
    for (int nt = 0; nt < 4; ++nt)
      acc[m][nt] = (f32x4){0.f, 0.f, 0.f, 0.f};

  const float* xb = x + (size_t)b * CIN * HW;

// pack S as round-to-nearest bf16 pairs, single flavor
#define GATHER(MW, MI, FASTE, ROW)                                              \
  {                                                                             \
    float s0_, s1_, s2_, s3_;                                                   \
    if (FASTE) {                                                                \
      float4 T0 = *(const float4*)&win[(MI.x - ob) * 4];                        \
      float4 T1 = *(const float4*)&win[(MI.y - ob) * 4];                        \
      float4 T2 = *(const float4*)&win[(MI.z - ob) * 4];                        \
      float4 T3 = *(const float4*)&win[(MI.w - ob) * 4];                        \
      s0_ = MW.x * T0.x + MW.y * T1.x + MW.z * T2.x + MW.w * T3.x;              \
      s1_ = MW.x * T0.y + MW.y * T1.y + MW.z * T2.y + MW.w * T3.y;              \
      s2_ = MW.x * T0.z + MW.y * T1.z + MW.z * T2.z + MW.w * T3.z;              \
      s3_ = MW.x * T0.w + MW.y * T1.w + MW.z * T2.w + MW.w * T3.w;              \
    } else {                                                                    \
      const float* xc_ = xb + (size_t)c4 * HW;                                  \
      s0_ = MW.x * xc_[MI.x] + MW.y * xc_[MI.y] + MW.z * xc_[MI.z] + MW.w * xc_[MI.w]; \
      xc_ += HW;                                                                \
      s1_ = MW.x * xc_[MI.x] + MW.y * xc_[MI.y] + MW.z * xc_[MI.z] + MW.w * xc_[MI.w]; \
      xc_ += HW;                                                                \
      s2_ = MW.x * xc_[MI.x] + MW.y * xc_[MI.y] + MW.z * xc_[MI.z] + MW.w * xc_[MI.w]; \
      xc_ += HW;                                                                \
      s3_ = MW.x * xc_[MI.x] + MW.y * xc_[MI.y] + MW.z * xc_[MI.z] + MW.w * xc_[MI.w]; \
    }                                                                           \
    unsigned a0_ = __float_as_uint(s0_) + 0x8000u;                              \
    unsigned a1_ = __float_as_uint(s1_) + 0x8000u;                              \
    unsigned a2_ = __float_as_uint(s2_) + 0x8000u;                              \
    unsigned a3_ = __float_as_uint(s3_) + 0x8000u;                              \
    unsigned hiA_ = (a0_ >> 16) | (a1_ & 0xFFFF0000u);                          \
    unsigned hiB_ = (a2_ >> 16) | (a3_ & 0xFFFF0000u);                          \
    int cp0_ = 2 * step;                                                        \
    int quad_ = (((ROW) >> 2) + (cp0_ >> 2)) & 3;                               \
    int word_ = (ROW) * 16 + quad_ * 4 + (cp0_ & 3);                            \
    *(uint2*)&sbuf[word_] = make_uint2(hiA_, hiB_);                             \
  }

  for (int chunk = 0; chunk < CPC / 32; ++chunk) {
    int cbase = c0 + chunk * 32;
    for (int step = 0; step < 8; ++step) {
      int c4 = cbase + step * 4;
      {
        const float* xsb = xb + (size_t)(c4 + (t & 3)) * HW + ob + (t >> 2);
        int ldsbase = t & ~63;    // wave-uniform
#pragma unroll
        for (int j = 0; j < 8; ++j)
          __builtin_amdgcn_global_load_lds(
              (const __attribute__((address_space(1))) void*)(xsb + j * 64),
              (__attribute__((address_space(3))) void*)&win[j * 256 + ldsbase],
              4, 0, 0);
      }
      __syncthreads();
      GATHER(mw0, mi0, fast0, t)
      GATHER(mw1, mi1, fast1, 256 + t)
      if (hasC) GATHER(mw2, mi2, fast2, 512 + t)
      __syncthreads();
    }

    __builtin_amdgcn_s_setprio(1);
#pragma unroll
    for (int k = 0; k < 9; ++k) {
      short8v bh[4];
#pragma unroll
      for (int nt = 0; nt < 4; ++nt) {
        int row = k * 64 + nt * 16 + lrow;
        int quad = ((row >> 2) + lgrp) & 3;
        bh[nt] = *(const short8v*)&sbuf[row * 16 + quad * 4];
      }
#pragma unroll
      for (int m = 0; m < 2; ++m) {
        size_t widx = (((size_t)k * 32 + (cbase >> 3) + lgrp) * 128 + (wv * 32 + m * 16 + lrow)) * 8;
        short8v ah = *(const short8v*)(w_hi + widx);
        short8v al = *(const short8v*)(w_lo + widx);
#pragma unroll
        for (int nt = 0; nt < 4; ++nt) {
          acc[m][nt] = __builtin_amdgcn_mfma_f32_16x16x32_bf16(ah, bh[nt], acc[m][nt], 0, 0, 0);
          acc[m][nt] = __builtin_amdgcn_mfma_f32_16x16x32_bf16(al, bh[nt], acc[m][nt], 0, 0, 0);
        }
      }
    }
    __builtin_amdgcn_s_setprio(0);
    __syncthreads();
  }
#undef GATHER

#pragma unroll
  for (int m = 0; m < 2; ++m)
#pragma unroll
    for (int nt = 0; nt < 4; ++nt)
#pragma unroll
      for (int j = 0; j < 4; ++j) {
        int co = wv * 32 + m * 16 + lgrp * 4 + j;
        int p = h * 64 + nt * 16 + lrow;
        part[(((size_t)s2 * NB + b) * COUT + co) * HW + p] = acc[m][nt][j];
      }
}

// ---------------- fused reduce + bias + relu + 2x bilinear upsample (+XCD swizzle)
__global__ __launch_bounds__(256) void k_upred(
    const float* __restrict__ part, const float* __restrict__ bias_t,
    float* __restrict__ out)
{
  int bid = (blockIdx.x & 7) * 4096 + (blockIdx.x >> 3);  // bijective: 32768 = 8*4096
  int t = bid * 256 + threadIdx.x;
  if (t >= NB * COUT * 128 * 128) return;
  int j = t & 127;
  int i = (t >> 7) & 127;
  int bc = t >> 14;                 // b*COUT + co
  int co = bc & (COUT - 1);
  const float R = (float)(63.0 / 127.0);
  float pi = (float)i * R;
  float pj = (float)j * R;
  float i0f = floorf(pi), j0f = floorf(pj);
  int i0 = (int)i0f, j0 = (int)j0f;
  int i1 = min(i0 + 1, 63), j1 = min(j0 + 1, 63);
  float f = pi - i0f, g = pj - j0f;
  const float* p0 = part + (size_t)bc * HW;
  const float* p1 = part + (size_t)(CSPLIT - 1) * NB * COUT * HW + (size_t)bc * HW;
  float bv = bias_t[co];
  float a  = fmaxf(p0[i0 * 64 + j0] + p1[i0 * 64 + j0] + bv, 0.f);
  float bb = fmaxf(p0[i0 * 64 + j1] + p1[i0 * 64 + j1] + bv, 0.f);
  float cc = fmaxf(p0[i1 * 64 + j0] + p1[i1 * 64 + j0] + bv, 0.f);
  float dd = fmaxf(p0[i1 * 64 + j1] + p1[i1 * 64 + j1] + bv, 0.f);
  float t0 = a * (1.f - f) + cc * f;
  float t1 = bb * (1.f - f) + dd * f;
  out[t] = t0 * (1.f - g) + t1 * g;
}

extern "C" void kernel_launch(void* const* d_in, const int* in_sizes, int n_in,
                              void* d_out, int out_size, void* d_ws, size_t ws_size,
                              hipStream_t stream)
{
  const float* x     = (const float*)d_in[0];
  const float* w_off = (const float*)d_in[1];
  const float* b_off = (const float*)d_in[2];
  const float* w_dcn = (const float*)d_in[3];
  const float* b_dcn = (const float*)d_in[4];
  const float* gamma = (const float*)d_in[5];
  const float* beta  = (const float*)d_in[6];
  const float* rmean = (const float*)d_in[7];
  const float* rvar  = (const float*)d_in[8];
  float* out = (float*)d_out;

  char* ws = (char*)d_ws;
  size_t off = 0;
  auto alloc = [&](size_t bytes) {
    void* p = ws + off;
    off = (off + bytes + 255) & ~255UL;
    return p;
  };
  float*  om_part = (float*) alloc(sizeof(float)  * OCSPLIT * NB * 27 * HW);
  float4* md_w    = (float4*)alloc(sizeof(float4) * NB * 9 * HW);
  int4*   md_i    = (int4*)  alloc(sizeof(int4)   * NB * 9 * HW);
  unsigned short* w_hi = (unsigned short*)alloc(sizeof(unsigned short) * 9 * CIN * COUT);
  unsigned short* w_lo = (unsigned short*)alloc(sizeof(unsigned short) * 9 * CIN * COUT);
  unsigned short* wo_hi = (unsigned short*)alloc(sizeof(unsigned short) * 9 * 32 * 32 * 8);
  unsigned short* wo_lo = (unsigned short*)alloc(sizeof(unsigned short) * 9 * 32 * 32 * 8);
  float*  bias_t  = (float*) alloc(sizeof(float)  * COUT);
  float*  part    = (float*) alloc(sizeof(float)  * CSPLIT * NB * COUT * HW);
  (void)ws_size; (void)in_sizes; (void)n_in; (void)out_size;

  k_prep_w<<<(CIN * COUT * 9 + 255) / 256, 256, 0, stream>>>(
      w_dcn, b_dcn, gamma, beta, rmean, rvar, w_hi, w_lo, bias_t);
  k_prep_wo<<<(9 * 32 * 32 * 8 + 255) / 256, 256, 0, stream>>>(w_off, wo_hi, wo_lo);
  k_off_mfma<<<NB * 64 * 4, 256, 0, stream>>>(x, wo_hi, wo_lo, om_part);
  k_prep_md<<<(NB * 9 * HW + 255) / 256, 256, 0, stream>>>(om_part, b_off, md_w, md_i);
  k_dcn<<<CSPLIT * NB * 64, 256, 0, stream>>>(x, w_hi, w_lo, md_w, md_i, part);
  k_upred<<<(NB * COUT * 128 * 128 + 255) / 256, 256, 0, stream>>>(part, bias_t, out);
}

// Round 29
// 101.494 us; speedup vs baseline: 1.1422x; 1.0311x over previous
//
#include <hip/hip_runtime.h>
#include <math.h>

#define CIN  256
#define COUT 128
#define HW   4096
#define NB   4
#define OCSPLIT 4
#define CSPLIT  2
#define CPC  (CIN / CSPLIT)      // 128 channels per k_dcn block (4 chunks of 32)
#define SFLAV (576 * 16)         // u32 words in k_dcn sbuf (hi flavor only)

typedef short short8v __attribute__((ext_vector_type(8)));
typedef float f32x4  __attribute__((ext_vector_type(4)));

// ---------------- weight prep (DCN): bf16 hi/lo split, fragment-ready layout
__global__ __launch_bounds__(256) void k_prep_w(
    const float* __restrict__ w_dcn, const float* __restrict__ b_dcn,
    const float* __restrict__ gamma, const float* __restrict__ beta,
    const float* __restrict__ rmean, const float* __restrict__ rvar,
    unsigned short* __restrict__ w_hi, unsigned short* __restrict__ w_lo,
    float* __restrict__ bias_t)
{
  int t = blockIdx.x * 256 + threadIdx.x;
  if (t < COUT) {
    float sc = gamma[t] * rsqrtf(rvar[t] + 1e-5f);
    bias_t[t] = b_dcn[t] * sc + beta[t] - rmean[t] * sc;
  }
  if (t >= CIN * COUT * 9) return;
  int k = t % 9;
  int q = t / 9;
  int co = q % COUT;
  int c  = q / COUT;
  float sc = gamma[co] * rsqrtf(rvar[co] + 1e-5f);
  float w = w_dcn[((size_t)co * CIN + c) * 9 + k] * sc;
  unsigned int wb = __float_as_uint(w);
  unsigned short hi = (unsigned short)(wb >> 16);
  float lof = w - __uint_as_float(wb & 0xFFFF0000u);
  unsigned short lo = (unsigned short)(__float_as_uint(lof) >> 16);
  size_t idx = (((size_t)k * 32 + (c >> 3)) * 128 + co) * 8 + (c & 7);
  w_hi[idx] = hi;
  w_lo[idx] = lo;
}

// ---------------- weight prep (offset conv): [k][cq][co32][8ch], co>=27 zero
__global__ __launch_bounds__(256) void k_prep_wo(
    const float* __restrict__ w_off,
    unsigned short* __restrict__ wo_hi, unsigned short* __restrict__ wo_lo)
{
  int t = blockIdx.x * 256 + threadIdx.x;
  if (t >= 9 * 32 * 32 * 8) return;
  int ce = t & 7;
  int co = (t >> 3) & 31;
  int cq = (t >> 8) & 31;
  int k  = t >> 13;
  int c = cq * 8 + ce;
  float w = (co < 27) ? w_off[((size_t)co * CIN + c) * 9 + k] : 0.f;
  unsigned int wb = __float_as_uint(w);
  unsigned short hi = (unsigned short)(wb >> 16);
  float lof = w - __uint_as_float(wb & 0xFFFF0000u);
  unsigned short lo = (unsigned short)(__float_as_uint(lof) >> 16);
  wo_hi[t] = hi;
  wo_lo[t] = lo;
}

// ---------------- offset conv via MFMA (R20) + XCD swizzle (grid 1024 = 8 x 128)
__global__ __launch_bounds__(256, 4) void k_off_mfma(
    const float* __restrict__ x,
    const unsigned short* __restrict__ wo_hi, const unsigned short* __restrict__ wo_lo,
    float* __restrict__ om_part)
{
  int blk = (blockIdx.x & 7) * 128 + (blockIdx.x >> 3);  // bijective: 1024 = 8*128
  int split = blk & 3;
  int bh = blk >> 2;
  int b = bh >> 6, h = bh & 63;
  int t = threadIdx.x;
  int lane = t & 63;
  int wv = t >> 6;
  int lrow = lane & 15, lgrp = lane >> 4;

  __shared__ __align__(16) unsigned int win_hi[3 * 66 * 20];
  __shared__ __align__(16) unsigned int win_lo[3 * 66 * 20];

  f32x4 acc[2];
  acc[0] = (f32x4){0.f, 0.f, 0.f, 0.f};
  acc[1] = (f32x4){0.f, 0.f, 0.f, 0.f};

  const float* xb = x + (size_t)b * CIN * HW;

  for (int chunk = 0; chunk < 2; ++chunk) {
    int cbase = split * 64 + chunk * 32;
    for (int i = t; i < 3168; i += 256) {
      int cp = i / 198;
      int s  = i - cp * 198;
      int r  = s / 66;
      int colp = s - r * 66;
      int row = h + r - 1;
      int col = colp - 1;
      bool v = ((unsigned)row < 64u) && ((unsigned)col < 64u);
      int ch = cbase + 2 * cp;
      float f0 = 0.f, f1 = 0.f;
      if (v) {
        const float* xp = xb + ((size_t)ch * 64 + row) * 64 + col;
        f0 = xp[0];
        f1 = xp[HW];
      }
      unsigned a0 = __float_as_uint(f0), a1 = __float_as_uint(f1);
      unsigned hi = (a0 >> 16) | (a1 & 0xFFFF0000u);
      float l0 = f0 - __uint_as_float(a0 & 0xFFFF0000u);
      float l1 = f1 - __uint_as_float(a1 & 0xFFFF0000u);
      unsigned lo = (__float_as_uint(l0) >> 16) | (__float_as_uint(l1) & 0xFFFF0000u);
      win_hi[s * 20 + cp] = hi;
      win_lo[s * 20 + cp] = lo;
    }
    __syncthreads();

    int pos = wv * 16 + lrow;
#pragma unroll
    for (int k = 0; k < 9; ++k) {
      int ky = k / 3 - 1, kx = k % 3 - 1;
      int slot = (ky + 1) * 66 + pos + kx + 1;
      const unsigned int* ph = &win_hi[slot * 20 + lgrp * 4];
      const unsigned int* pl = &win_lo[slot * 20 + lgrp * 4];
      short8v bh = *(const short8v*)ph;
      short8v bl = *(const short8v*)pl;
#pragma unroll
      for (int m = 0; m < 2; ++m) {
        size_t widx = (((size_t)k * 32 + (cbase >> 3) + lgrp) * 32 + m * 16 + lrow) * 8;
        short8v ah = *(const short8v*)(wo_hi + widx);
        short8v al = *(const short8v*)(wo_lo + widx);
        acc[m] = __builtin_amdgcn_mfma_f32_16x16x32_bf16(ah, bh, acc[m], 0, 0, 0);
        acc[m] = __builtin_amdgcn_mfma_f32_16x16x32_bf16(ah, bl, acc[m], 0, 0, 0);
        acc[m] = __builtin_amdgcn_mfma_f32_16x16x32_bf16(al, bh, acc[m], 0, 0, 0);
      }
    }
    __syncthreads();
  }

  int pos = wv * 16 + lrow;
#pragma unroll
  for (int m = 0; m < 2; ++m)
#pragma unroll
    for (int j = 0; j < 4; ++j) {
      int co = m * 16 + lgrp * 4 + j;
      if (co < 27)
        om_part[(((size_t)split * NB + b) * 27 + co) * HW + h * 64 + pos] = acc[m][j];
    }
}

// ---------------- sampling metadata (sums OCSPLIT=4 partials)
__global__ __launch_bounds__(256) void k_prep_md(
    const float* __restrict__ om_part, const float* __restrict__ b_off,
    float4* __restrict__ md_w, int4* __restrict__ md_i)
{
  int t = blockIdx.x * 256 + threadIdx.x;
  if (t >= NB * 9 * HW) return;
  int hw = t & 4095;
  int bk = t >> 12;
  int k = bk % 9;
  int b = bk / 9;
  int h = hw >> 6, w = hw & 63;

  float dy = b_off[2 * k], dx = b_off[2 * k + 1], mr = b_off[18 + k];
#pragma unroll
  for (int s = 0; s < OCSPLIT; ++s) {
    size_t o = ((size_t)s * NB + b) * 27 * HW + hw;
    dy += om_part[o + (size_t)(2 * k) * HW];
    dx += om_part[o + (size_t)(2 * k + 1) * HW];
    mr += om_part[o + (size_t)(18 + k) * HW];
  }
  float m = 1.0f / (1.0f + expf(-mr));

  int ky = k / 3 - 1, kx = k % 3 - 1;
  float py = dy + (float)h + (float)ky;
  float px = dx + (float)w + (float)kx;
  float y0f = floorf(py), x0f = floorf(px);
  float fy = py - y0f, fx = px - x0f;
  int y0 = (int)y0f, x0 = (int)x0f;
  int y1 = y0 + 1, x1 = x0 + 1;

  bool vy0 = (y0 >= 0) & (y0 < 64), vy1 = (y1 >= 0) & (y1 < 64);
  bool vx0 = (x0 >= 0) & (x0 < 64), vx1 = (x1 >= 0) & (x1 < 64);
  int cy0 = min(max(y0, 0), 63), cy1 = min(max(y1, 0), 63);
  int cx0 = min(max(x0, 0), 63), cx1 = min(max(x1, 0), 63);

  float4 wv;
  wv.x = (vy0 && vx0) ? (1.f - fy) * (1.f - fx) * m : 0.f;
  wv.y = (vy0 && vx1) ? (1.f - fy) * fx * m : 0.f;
  wv.z = (vy1 && vx0) ? fy * (1.f - fx) * m : 0.f;
  wv.w = (vy1 && vx1) ? fy * fx * m : 0.f;
  int4 iv;
  iv.x = cy0 * 64 + cx0;
  iv.y = cy0 * 64 + cx1;
  iv.z = cy1 * 64 + cx0;
  iv.w = cy1 * 64 + cx1;
  md_w[t] = wv;
  md_i[t] = iv;
}

// ---------------- DCN: P=64 channel-last LDS window + MFMA (R25/R28, validated best)
// S rounded bf16 (2-term MFMA), XCD swizzle, async staging. LDS 45056 B.
__global__ __launch_bounds__(256, 3) void k_dcn(
    const float* __restrict__ x,
    const unsigned short* __restrict__ w_hi, const unsigned short* __restrict__ w_lo,
    const float4* __restrict__ md_w, const int4* __restrict__ md_i,
    float* __restrict__ part)
{
  int blk = (blockIdx.x & 7) * 64 + (blockIdx.x >> 3);  // bijective: 512 = 8*64
  int h = blk & 63;
  int b = (blk >> 6) & (NB - 1);
  int s2 = blk >> 8;
  int c0 = s2 * CPC;
  int t = threadIdx.x;
  int lane = t & 63;
  int wv = t >> 6;
  int lrow = lane & 15, lgrp = lane >> 4;

  __shared__ __align__(16) unsigned int sbuf[SFLAV];      // 36864 B (hi only)
  __shared__ __align__(16) float win[8 * 64 * 4];         // 8192 B, channel-last

  int W0 = min(max(h - 3, 0), 56);
  int ob = W0 * 64;

  int k0 = t >> 6;
  size_t mdbase = (size_t)b * 9 * HW;
  size_t mdp = mdbase + (size_t)h * 64 + (t & 63);
  float4 mw0 = md_w[mdp + (size_t)k0 * HW];
  int4  mi0 = md_i[mdp + (size_t)k0 * HW];
  float4 mw1 = md_w[mdp + (size_t)(k0 + 4) * HW];
  int4  mi1 = md_i[mdp + (size_t)(k0 + 4) * HW];
  bool hasC = (t < 64);
  float4 mw2 = make_float4(0.f, 0.f, 0.f, 0.f);
  int4  mi2 = make_int4(0, 0, 0, 0);
  if (hasC) {
    mw2 = md_w[mdp + (size_t)8 * HW];
    mi2 = md_i[mdp + (size_t)8 * HW];
  }
  int fast0 = __all(((unsigned)(mi0.x - ob) < 512u) && ((unsigned)(mi0.z - ob) < 512u));
  int fast1 = __all(((unsigned)(mi1.x - ob) < 512u) && ((unsigned)(mi1.z - ob) < 512u));
  int fast2 = __all(((unsigned)(mi2.x - ob) < 512u) && ((unsigned)(mi2.z - ob) < 512u));

  f32x4 acc[2][4];
#pragma unroll
  for (int m = 0; m < 2; ++m)
#pragma unroll
    for (int nt = 0; nt < 4; ++nt)
      acc[m][nt] = (f32x4){0.f, 0.f, 0.f, 0.f};

  const float* xb = x + (size_t)b * CIN * HW;

// pack S as round-to-nearest bf16 pairs, single flavor
#define GATHER(MW, MI, FASTE, ROW)                                              \
  {                                                                             \
    float s0_, s1_, s2_, s3_;                                                   \
    if (FASTE) {                                                                \
      float4 T0 = *(const float4*)&win[(MI.x - ob) * 4];                        \
      float4 T1 = *(const float4*)&win[(MI.y - ob) * 4];                        \
      float4 T2 = *(const float4*)&win[(MI.z - ob) * 4];                        \
      float4 T3 = *(const float4*)&win[(MI.w - ob) * 4];                        \
      s0_ = MW.x * T0.x + MW.y * T1.x + MW.z * T2.x + MW.w * T3.x;              \
      s1_ = MW.x * T0.y + MW.y * T1.y + MW.z * T2.y + MW.w * T3.y;              \
      s2_ = MW.x * T0.z + MW.y * T1.z + MW.z * T2.z + MW.w * T3.z;              \
      s3_ = MW.x * T0.w + MW.y * T1.w + MW.z * T2.w + MW.w * T3.w;              \
    } else {                                                                    \
      const float* xc_ = xb + (size_t)c4 * HW;                                  \
      s0_ = MW.x * xc_[MI.x] + MW.y * xc_[MI.y] + MW.z * xc_[MI.z] + MW.w * xc_[MI.w]; \
      xc_ += HW;                                                                \
      s1_ = MW.x * xc_[MI.x] + MW.y * xc_[MI.y] + MW.z * xc_[MI.z] + MW.w * xc_[MI.w]; \
      xc_ += HW;                                                                \
      s2_ = MW.x * xc_[MI.x] + MW.y * xc_[MI.y] + MW.z * xc_[MI.z] + MW.w * xc_[MI.w]; \
      xc_ += HW;                                                                \
      s3_ = MW.x * xc_[MI.x] + MW.y * xc_[MI.y] + MW.z * xc_[MI.z] + MW.w * xc_[MI.w]; \
    }                                                                           \
    unsigned a0_ = __float_as_uint(s0_) + 0x8000u;                              \
    unsigned a1_ = __float_as_uint(s1_) + 0x8000u;                              \
    unsigned a2_ = __float_as_uint(s2_) + 0x8000u;                              \
    unsigned a3_ = __float_as_uint(s3_) + 0x8000u;                              \
    unsigned hiA_ = (a0_ >> 16) | (a1_ & 0xFFFF0000u);                          \
    unsigned hiB_ = (a2_ >> 16) | (a3_ & 0xFFFF0000u);                          \
    int cp0_ = 2 * step;                                                        \
    int quad_ = (((ROW) >> 2) + (cp0_ >> 2)) & 3;                               \
    int word_ = (ROW) * 16 + quad_ * 4 + (cp0_ & 3);                            \
    *(uint2*)&sbuf[word_] = make_uint2(hiA_, hiB_);                             \
  }

  for (int chunk = 0; chunk < CPC / 32; ++chunk) {
    int cbase = c0 + chunk * 32;
    for (int step = 0; step < 8; ++step) {
      int c4 = cbase + step * 4;
      {
        const float* xsb = xb + (size_t)(c4 + (t & 3)) * HW + ob + (t >> 2);
        int ldsbase = t & ~63;    // wave-uniform
#pragma unroll
        for (int j = 0; j < 8; ++j)
          __builtin_amdgcn_global_load_lds(
              (const __attribute__((address_space(1))) void*)(xsb + j * 64),
              (__attribute__((address_space(3))) void*)&win[j * 256 + ldsbase],
              4, 0, 0);
      }
      __syncthreads();
      GATHER(mw0, mi0, fast0, t)
      GATHER(mw1, mi1, fast1, 256 + t)
      if (hasC) GATHER(mw2, mi2, fast2, 512 + t)
      __syncthreads();
    }

    __builtin_amdgcn_s_setprio(1);
#pragma unroll
    for (int k = 0; k < 9; ++k) {
      short8v bh[4];
#pragma unroll
      for (int nt = 0; nt < 4; ++nt) {
        int row = k * 64 + nt * 16 + lrow;
        int quad = ((row >> 2) + lgrp) & 3;
        bh[nt] = *(const short8v*)&sbuf[row * 16 + quad * 4];
      }
#pragma unroll
      for (int m = 0; m < 2; ++m) {
        size_t widx = (((size_t)k * 32 + (cbase >> 3) + lgrp) * 128 + (wv * 32 + m * 16 + lrow)) * 8;
        short8v ah = *(const short8v*)(w_hi + widx);
        short8v al = *(const short8v*)(w_lo + widx);
#pragma unroll
        for (int nt = 0; nt < 4; ++nt) {
          acc[m][nt] = __builtin_amdgcn_mfma_f32_16x16x32_bf16(ah, bh[nt], acc[m][nt], 0, 0, 0);
          acc[m][nt] = __builtin_amdgcn_mfma_f32_16x16x32_bf16(al, bh[nt], acc[m][nt], 0, 0, 0);
        }
      }
    }
    __builtin_amdgcn_s_setprio(0);
    __syncthreads();
  }
#undef GATHER

#pragma unroll
  for (int m = 0; m < 2; ++m)
#pragma unroll
    for (int nt = 0; nt < 4; ++nt)
#pragma unroll
      for (int j = 0; j < 4; ++j) {
        int co = wv * 32 + m * 16 + lgrp * 4 + j;
        int p = h * 64 + nt * 16 + lrow;
        part[(((size_t)s2 * NB + b) * COUT + co) * HW + p] = acc[m][nt][j];
      }
}

// ---------------- fused reduce + bias + relu + 2x bilinear upsample
// j-pair tiled: each thread produces outputs (i, 2q) and (i, 2q+1) -> float2 store.
// Per-output math identical to reference order. +XCD swizzle (grid 16384 = 8 x 2048).
__global__ __launch_bounds__(256) void k_upred(
    const float* __restrict__ part, const float* __restrict__ bias_t,
    float* __restrict__ out)
{
  int bid = (blockIdx.x & 7) * 2048 + (blockIdx.x >> 3);  // bijective: 16384 = 8*2048
  int t = bid * 256 + threadIdx.x;
  if (t >= NB * COUT * 128 * 64) return;
  int q = t & 63;
  int i = (t >> 6) & 127;
  int bc = t >> 13;                 // b*COUT + co
  int co = bc & (COUT - 1);
  const float R = (float)(63.0 / 127.0);
  float pi = (float)i * R;
  float i0f = floorf(pi);
  int i0 = (int)i0f;
  int i1 = min(i0 + 1, 63);
  float f = pi - i0f;

  const float* p0 = part + (size_t)bc * HW;
  const float* p1 = part + (size_t)(CSPLIT - 1) * NB * COUT * HW + (size_t)bc * HW;
  const float* r00 = p0 + i0 * 64;  // split0 row i0
  const float* r01 = p0 + i1 * 64;  // split0 row i1
  const float* r10 = p1 + i0 * 64;  // split1 row i0
  const float* r11 = p1 + i1 * 64;  // split1 row i1
  float bv = bias_t[co];

  float2 res;
#pragma unroll
  for (int e = 0; e < 2; ++e) {
    int j = 2 * q + e;
    float pj = (float)j * R;
    float j0f = floorf(pj);
    int j0 = (int)j0f;
    int j1 = min(j0 + 1, 63);
    float g = pj - j0f;
    float a  = fmaxf(r00[j0] + r10[j0] + bv, 0.f);
    float bb = fmaxf(r00[j1] + r10[j1] + bv, 0.f);
    float cc = fmaxf(r01[j0] + r11[j0] + bv, 0.f);
    float dd = fmaxf(r01[j1] + r11[j1] + bv, 0.f);
    float t0 = a * (1.f - f) + cc * f;
    float t1 = bb * (1.f - f) + dd * f;
    float v = t0 * (1.f - g) + t1 * g;
    if (e == 0) res.x = v; else res.y = v;
  }
  *(float2*)&out[(size_t)bc * 16384 + i * 128 + 2 * q] = res;
}

extern "C" void kernel_launch(void* const* d_in, const int* in_sizes, int n_in,
                              void* d_out, int out_size, void* d_ws, size_t ws_size,
                              hipStream_t stream)
{
  const float* x     = (const float*)d_in[0];
  const float* w_off = (const float*)d_in[1];
  const float* b_off = (const float*)d_in[2];
  const float* w_dcn = (const float*)d_in[3];
  const float* b_dcn = (const float*)d_in[4];
  const float* gamma = (const float*)d_in[5];
  const float* beta  = (const float*)d_in[6];
  const float* rmean = (const float*)d_in[7];
  const float* rvar  = (const float*)d_in[8];
  float* out = (float*)d_out;

  char* ws = (char*)d_ws;
  size_t off = 0;
  auto alloc = [&](size_t bytes) {
    void* p = ws + off;
    off = (off + bytes + 255) & ~255UL;
    return p;
  };
  float*  om_part = (float*) alloc(sizeof(float)  * OCSPLIT * NB * 27 * HW);
  float4* md_w    = (float4*)alloc(sizeof(float4) * NB * 9 * HW);
  int4*   md_i    = (int4*)  alloc(sizeof(int4)   * NB * 9 * HW);
  unsigned short* w_hi = (unsigned short*)alloc(sizeof(unsigned short) * 9 * CIN * COUT);
  unsigned short* w_lo = (unsigned short*)alloc(sizeof(unsigned short) * 9 * CIN * COUT);
  unsigned short* wo_hi = (unsigned short*)alloc(sizeof(unsigned short) * 9 * 32 * 32 * 8);
  unsigned short* wo_lo = (unsigned short*)alloc(sizeof(unsigned short) * 9 * 32 * 32 * 8);
  float*  bias_t  = (float*) alloc(sizeof(float)  * COUT);
  float*  part    = (float*) alloc(sizeof(float)  * CSPLIT * NB * COUT * HW);
  (void)ws_size; (void)in_sizes; (void)n_in; (void)out_size;

  k_prep_w<<<(CIN * COUT * 9 + 255) / 256, 256, 0, stream>>>(
      w_dcn, b_dcn, gamma, beta, rmean, rvar, w_hi, w_lo, bias_t);
  k_prep_wo<<<(9 * 32 * 32 * 8 + 255) / 256, 256, 0, stream>>>(w_off, wo_hi, wo_lo);
  k_off_mfma<<<NB * 64 * 4, 256, 0, stream>>>(x, wo_hi, wo_lo, om_part);
  k_prep_md<<<(NB * 9 * HW + 255) / 256, 256, 0, stream>>>(om_part, b_off, md_w, md_i);
  k_dcn<<<CSPLIT * NB * 64, 256, 0, stream>>>(x, w_hi, w_lo, md_w, md_i, part);
  k_upred<<<(NB * COUT * 128 * 64 + 255) / 256, 256, 0, stream>>>(part, bias_t, out);
}

// Round 30
// 100.667 us; speedup vs baseline: 1.1516x; 1.0082x over previous
//
#include <hip/hip_runtime.h>
#include <math.h>

#define CIN  256
#define COUT 128
#define HW   4096
#define NB   4
#define OCSPLIT 4
#define CSPLIT  2
#define CPC  (CIN / CSPLIT)      // 128 channels per k_dcn block (4 chunks of 32)
#define SFLAV (576 * 16)         // u32 words in k_dcn sbuf (hi flavor only)

typedef short short8v __attribute__((ext_vector_type(8)));
typedef float f32x4  __attribute__((ext_vector_type(4)));

// ---------------- weight prep (DCN): bf16 hi/lo split, fragment-ready layout
__global__ __launch_bounds__(256) void k_prep_w(
    const float* __restrict__ w_dcn, const float* __restrict__ b_dcn,
    const float* __restrict__ gamma, const float* __restrict__ beta,
    const float* __restrict__ rmean, const float* __restrict__ rvar,
    unsigned short* __restrict__ w_hi, unsigned short* __restrict__ w_lo,
    float* __restrict__ bias_t)
{
  int t = blockIdx.x * 256 + threadIdx.x;
  if (t < COUT) {
    float sc = gamma[t] * rsqrtf(rvar[t] + 1e-5f);
    bias_t[t] = b_dcn[t] * sc + beta[t] - rmean[t] * sc;
  }
  if (t >= CIN * COUT * 9) return;
  int k = t % 9;
  int q = t / 9;
  int co = q % COUT;
  int c  = q / COUT;
  float sc = gamma[co] * rsqrtf(rvar[co] + 1e-5f);
  float w = w_dcn[((size_t)co * CIN + c) * 9 + k] * sc;
  unsigned int wb = __float_as_uint(w);
  unsigned short hi = (unsigned short)(wb >> 16);
  float lof = w - __uint_as_float(wb & 0xFFFF0000u);
  unsigned short lo = (unsigned short)(__float_as_uint(lof) >> 16);
  size_t idx = (((size_t)k * 32 + (c >> 3)) * 128 + co) * 8 + (c & 7);
  w_hi[idx] = hi;
  w_lo[idx] = lo;
}

// ---------------- weight prep (offset conv): [k][cq][co32][8ch], co>=27 zero
__global__ __launch_bounds__(256) void k_prep_wo(
    const float* __restrict__ w_off,
    unsigned short* __restrict__ wo_hi, unsigned short* __restrict__ wo_lo)
{
  int t = blockIdx.x * 256 + threadIdx.x;
  if (t >= 9 * 32 * 32 * 8) return;
  int ce = t & 7;
  int co = (t >> 3) & 31;
  int cq = (t >> 8) & 31;
  int k  = t >> 13;
  int c = cq * 8 + ce;
  float w = (co < 27) ? w_off[((size_t)co * CIN + c) * 9 + k] : 0.f;
  unsigned int wb = __float_as_uint(w);
  unsigned short hi = (unsigned short)(wb >> 16);
  float lof = w - __uint_as_float(wb & 0xFFFF0000u);
  unsigned short lo = (unsigned short)(__float_as_uint(lof) >> 16);
  wo_hi[t] = hi;
  wo_lo[t] = lo;
}

// ---------------- offset conv via MFMA: x rounded bf16 only (2-term), W hi/lo split
// + XCD swizzle (grid 1024 = 8 x 128). LDS 15840 B.
__global__ __launch_bounds__(256, 4) void k_off_mfma(
    const float* __restrict__ x,
    const unsigned short* __restrict__ wo_hi, const unsigned short* __restrict__ wo_lo,
    float* __restrict__ om_part)
{
  int blk = (blockIdx.x & 7) * 128 + (blockIdx.x >> 3);  // bijective: 1024 = 8*128
  int split = blk & 3;
  int bh = blk >> 2;
  int b = bh >> 6, h = bh & 63;
  int t = threadIdx.x;
  int lane = t & 63;
  int wv = t >> 6;
  int lrow = lane & 15, lgrp = lane >> 4;

  __shared__ __align__(16) unsigned int win_hi[3 * 66 * 20];  // 15840 B

  f32x4 acc[2];
  acc[0] = (f32x4){0.f, 0.f, 0.f, 0.f};
  acc[1] = (f32x4){0.f, 0.f, 0.f, 0.f};

  const float* xb = x + (size_t)b * CIN * HW;

  for (int chunk = 0; chunk < 2; ++chunk) {
    int cbase = split * 64 + chunk * 32;
    for (int i = t; i < 3168; i += 256) {
      int cp = i / 198;
      int s  = i - cp * 198;
      int r  = s / 66;
      int colp = s - r * 66;
      int row = h + r - 1;
      int col = colp - 1;
      bool v = ((unsigned)row < 64u) && ((unsigned)col < 64u);
      int ch = cbase + 2 * cp;
      float f0 = 0.f, f1 = 0.f;
      if (v) {
        const float* xp = xb + ((size_t)ch * 64 + row) * 64 + col;
        f0 = xp[0];
        f1 = xp[HW];
      }
      unsigned a0 = __float_as_uint(f0) + 0x8000u;   // round-to-nearest bf16
      unsigned a1 = __float_as_uint(f1) + 0x8000u;
      win_hi[s * 20 + cp] = (a0 >> 16) | (a1 & 0xFFFF0000u);
    }
    __syncthreads();

    int pos = wv * 16 + lrow;
#pragma unroll
    for (int k = 0; k < 9; ++k) {
      int ky = k / 3 - 1, kx = k % 3 - 1;
      int slot = (ky + 1) * 66 + pos + kx + 1;
      short8v bhv = *(const short8v*)&win_hi[slot * 20 + lgrp * 4];
#pragma unroll
      for (int m = 0; m < 2; ++m) {
        size_t widx = (((size_t)k * 32 + (cbase >> 3) + lgrp) * 32 + m * 16 + lrow) * 8;
        short8v ah = *(const short8v*)(wo_hi + widx);
        short8v al = *(const short8v*)(wo_lo + widx);
        acc[m] = __builtin_amdgcn_mfma_f32_16x16x32_bf16(ah, bhv, acc[m], 0, 0, 0);
        acc[m] = __builtin_amdgcn_mfma_f32_16x16x32_bf16(al, bhv, acc[m], 0, 0, 0);
      }
    }
    __syncthreads();
  }

  int pos = wv * 16 + lrow;
#pragma unroll
  for (int m = 0; m < 2; ++m)
#pragma unroll
    for (int j = 0; j < 4; ++j) {
      int co = m * 16 + lgrp * 4 + j;
      if (co < 27)
        om_part[(((size_t)split * NB + b) * 27 + co) * HW + h * 64 + pos] = acc[m][j];
    }
}

// ---------------- sampling metadata (sums OCSPLIT=4 partials)
__global__ __launch_bounds__(256) void k_prep_md(
    const float* __restrict__ om_part, const float* __restrict__ b_off,
    float4* __restrict__ md_w, int4* __restrict__ md_i)
{
  int t = blockIdx.x * 256 + threadIdx.x;
  if (t >= NB * 9 * HW) return;
  int hw = t & 4095;
  int bk = t >> 12;
  int k = bk % 9;
  int b = bk / 9;
  int h = hw >> 6, w = hw & 63;

  float dy = b_off[2 * k], dx = b_off[2 * k + 1], mr = b_off[18 + k];
#pragma unroll
  for (int s = 0; s < OCSPLIT; ++s) {
    size_t o = ((size_t)s * NB + b) * 27 * HW + hw;
    dy += om_part[o + (size_t)(2 * k) * HW];
    dx += om_part[o + (size_t)(2 * k + 1) * HW];
    mr += om_part[o + (size_t)(18 + k) * HW];
  }
  float m = 1.0f / (1.0f + expf(-mr));

  int ky = k / 3 - 1, kx = k % 3 - 1;
  float py = dy + (float)h + (float)ky;
  float px = dx + (float)w + (float)kx;
  float y0f = floorf(py), x0f = floorf(px);
  float fy = py - y0f, fx = px - x0f;
  int y0 = (int)y0f, x0 = (int)x0f;
  int y1 = y0 + 1, x1 = x0 + 1;

  bool vy0 = (y0 >= 0) & (y0 < 64), vy1 = (y1 >= 0) & (y1 < 64);
  bool vx0 = (x0 >= 0) & (x0 < 64), vx1 = (x1 >= 0) & (x1 < 64);
  int cy0 = min(max(y0, 0), 63), cy1 = min(max(y1, 0), 63);
  int cx0 = min(max(x0, 0), 63), cx1 = min(max(x1, 0), 63);

  float4 wv;
  wv.x = (vy0 && vx0) ? (1.f - fy) * (1.f - fx) * m : 0.f;
  wv.y = (vy0 && vx1) ? (1.f - fy) * fx * m : 0.f;
  wv.z = (vy1 && vx0) ? fy * (1.f - fx) * m : 0.f;
  wv.w = (vy1 && vx1) ? fy * fx * m : 0.f;
  int4 iv;
  iv.x = cy0 * 64 + cx0;
  iv.y = cy0 * 64 + cx1;
  iv.z = cy1 * 64 + cx0;
  iv.w = cy1 * 64 + cx1;
  md_w[t] = wv;
  md_i[t] = iv;
}

// ---------------- DCN: P=64 channel-last LDS window + MFMA (R25/R28, validated best)
// S rounded bf16 (2-term MFMA), XCD swizzle, async staging. LDS 45056 B.
__global__ __launch_bounds__(256, 3) void k_dcn(
    const float* __restrict__ x,
    const unsigned short* __restrict__ w_hi, const unsigned short* __restrict__ w_lo,
    const float4* __restrict__ md_w, const int4* __restrict__ md_i,
    float* __restrict__ part)
{
  int blk = (blockIdx.x & 7) * 64 + (blockIdx.x >> 3);  // bijective: 512 = 8*64
  int h = blk & 63;
  int b = (blk >> 6) & (NB - 1);
  int s2 = blk >> 8;
  int c0 = s2 * CPC;
  int t = threadIdx.x;
  int lane = t & 63;
  int wv = t >> 6;
  int lrow = lane & 15, lgrp = lane >> 4;

  __shared__ __align__(16) unsigned int sbuf[SFLAV];      // 36864 B (hi only)
  __shared__ __align__(16) float win[8 * 64 * 4];         // 8192 B, channel-last

  int W0 = min(max(h - 3, 0), 56);
  int ob = W0 * 64;

  int k0 = t >> 6;
  size_t mdbase = (size_t)b * 9 * HW;
  size_t mdp = mdbase + (size_t)h * 64 + (t & 63);
  float4 mw0 = md_w[mdp + (size_t)k0 * HW];
  int4  mi0 = md_i[mdp + (size_t)k0 * HW];
  float4 mw1 = md_w[mdp + (size_t)(k0 + 4) * HW];
  int4  mi1 = md_i[mdp + (size_t)(k0 + 4) * HW];
  bool hasC = (t < 64);
  float4 mw2 = make_float4(0.f, 0.f, 0.f, 0.f);
  int4  mi2 = make_int4(0, 0, 0, 0);
  if (hasC) {
    mw2 = md_w[mdp + (size_t)8 * HW];
    mi2 = md_i[mdp + (size_t)8 * HW];
  }
  int fast0 = __all(((unsigned)(mi0.x - ob) < 512u) && ((unsigned)(mi0.z - ob) < 512u));
  int fast1 = __all(((unsigned)(mi1.x - ob) < 512u) && ((unsigned)(mi1.z - ob) < 512u));
  int fast2 = __all(((unsigned)(mi2.x - ob) < 512u) && ((unsigned)(mi2.z - ob) < 512u));

  f32x4 acc[2][4];
#pragma unroll
  for (int m = 0; m < 2; ++m)
#pragma unroll
    for (int nt = 0; nt < 4; ++nt)
      acc[m][nt] = (f32x4){0.f, 0.f, 0.f, 0.f};

  const float* xb = x + (size_t)b * CIN * HW;

// pack S as round-to-nearest bf16 pairs, single flavor
#define GATHER(MW, MI, FASTE, ROW)                                              \
  {                                                                             \
    float s0_, s1_, s2_, s3_;                                                   \
    if (FASTE) {                                                                \
      float4 T0 = *(const float4*)&win[(MI.x - ob) * 4];                        \
      float4 T1 = *(const float4*)&win[(MI.y - ob) * 4];                        \
      float4 T2 = *(const float4*)&win[(MI.z - ob) * 4];                        \
      float4 T3 = *(const float4*)&win[(MI.w - ob) * 4];                        \
      s0_ = MW.x * T0.x + MW.y * T1.x + MW.z * T2.x + MW.w * T3.x;              \
      s1_ = MW.x * T0.y + MW.y * T1.y + MW.z * T2.y + MW.w * T3.y;              \
      s2_ = MW.x * T0.z + MW.y * T1.z + MW.z * T2.z + MW.w * T3.z;              \
      s3_ = MW.x * T0.w + MW.y * T1.w + MW.z * T2.w + MW.w * T3.w;              \
    } else {                                                                    \
      const float* xc_ = xb + (size_t)c4 * HW;                                  \
      s0_ = MW.x * xc_[MI.x] + MW.y * xc_[MI.y] + MW.z * xc_[MI.z] + MW.w * xc_[MI.w]; \
      xc_ += HW;                                                                \
      s1_ = MW.x * xc_[MI.x] + MW.y * xc_[MI.y] + MW.z * xc_[MI.z] + MW.w * xc_[MI.w]; \
      xc_ += HW;                                                                \
      s2_ = MW.x * xc_[MI.x] + MW.y * xc_[MI.y] + MW.z * xc_[MI.z] + MW.w * xc_[MI.w]; \
      xc_ += HW;                                                                \
      s3_ = MW.x * xc_[MI.x] + MW.y * xc_[MI.y] + MW.z * xc_[MI.z] + MW.w * xc_[MI.w]; \
    }                                                                           \
    unsigned a0_ = __float_as_uint(s0_) + 0x8000u;                              \
    unsigned a1_ = __float_as_uint(s1_) + 0x8000u;                              \
    unsigned a2_ = __float_as_uint(s2_) + 0x8000u;                              \
    unsigned a3_ = __float_as_uint(s3_) + 0x8000u;                              \
    unsigned hiA_ = (a0_ >> 16) | (a1_ & 0xFFFF0000u);                          \
    unsigned hiB_ = (a2_ >> 16) | (a3_ & 0xFFFF0000u);                          \
    int cp0_ = 2 * step;                                                        \
    int quad_ = (((ROW) >> 2) + (cp0_ >> 2)) & 3;                               \
    int word_ = (ROW) * 16 + quad_ * 4 + (cp0_ & 3);                            \
    *(uint2*)&sbuf[word_] = make_uint2(hiA_, hiB_);                             \
  }

  for (int chunk = 0; chunk < CPC / 32; ++chunk) {
    int cbase = c0 + chunk * 32;
    for (int step = 0; step < 8; ++step) {
      int c4 = cbase + step * 4;
      {
        const float* xsb = xb + (size_t)(c4 + (t & 3)) * HW + ob + (t >> 2);
        int ldsbase = t & ~63;    // wave-uniform
#pragma unroll
        for (int j = 0; j < 8; ++j)
          __builtin_amdgcn_global_load_lds(
              (const __attribute__((address_space(1))) void*)(xsb + j * 64),
              (__attribute__((address_space(3))) void*)&win[j * 256 + ldsbase],
              4, 0, 0);
      }
      __syncthreads();
      GATHER(mw0, mi0, fast0, t)
      GATHER(mw1, mi1, fast1, 256 + t)
      if (hasC) GATHER(mw2, mi2, fast2, 512 + t)
      __syncthreads();
    }

    __builtin_amdgcn_s_setprio(1);
#pragma unroll
    for (int k = 0; k < 9; ++k) {
      short8v bh[4];
#pragma unroll
      for (int nt = 0; nt < 4; ++nt) {
        int row = k * 64 + nt * 16 + lrow;
        int quad = ((row >> 2) + lgrp) & 3;
        bh[nt] = *(const short8v*)&sbuf[row * 16 + quad * 4];
      }
#pragma unroll
      for (int m = 0; m < 2; ++m) {
        size_t widx = (((size_t)k * 32 + (cbase >> 3) + lgrp) * 128 + (wv * 32 + m * 16 + lrow)) * 8;
        short8v ah = *(const short8v*)(w_hi + widx);
        short8v al = *(const short8v*)(w_lo + widx);
#pragma unroll
        for (int nt = 0; nt < 4; ++nt) {
          acc[m][nt] = __builtin_amdgcn_mfma_f32_16x16x32_bf16(ah, bh[nt], acc[m][nt], 0, 0, 0);
          acc[m][nt] = __builtin_amdgcn_mfma_f32_16x16x32_bf16(al, bh[nt], acc[m][nt], 0, 0, 0);
        }
      }
    }
    __builtin_amdgcn_s_setprio(0);
    __syncthreads();
  }
#undef GATHER

#pragma unroll
  for (int m = 0; m < 2; ++m)
#pragma unroll
    for (int nt = 0; nt < 4; ++nt)
#pragma unroll
      for (int j = 0; j < 4; ++j) {
        int co = wv * 32 + m * 16 + lgrp * 4 + j;
        int p = h * 64 + nt * 16 + lrow;
        part[(((size_t)s2 * NB + b) * COUT + co) * HW + p] = acc[m][nt][j];
      }
}

// ---------------- fused reduce + bias + relu + 2x bilinear upsample
// j-pair tiled (R29, validated) + XCD swizzle (grid 16384 = 8 x 2048).
__global__ __launch_bounds__(256) void k_upred(
    const float* __restrict__ part, const float* __restrict__ bias_t,
    float* __restrict__ out)
{
  int bid = (blockIdx.x & 7) * 2048 + (blockIdx.x >> 3);  // bijective: 16384 = 8*2048
  int t = bid * 256 + threadIdx.x;
  if (t >= NB * COUT * 128 * 64) return;
  int q = t & 63;
  int i = (t >> 6) & 127;
  int bc = t >> 13;                 // b*COUT + co
  int co = bc & (COUT - 1);
  const float R = (float)(63.0 / 127.0);
  float pi = (float)i * R;
  float i0f = floorf(pi);
  int i0 = (int)i0f;
  int i1 = min(i0 + 1, 63);
  float f = pi - i0f;

  const float* p0 = part + (size_t)bc * HW;
  const float* p1 = part + (size_t)(CSPLIT - 1) * NB * COUT * HW + (size_t)bc * HW;
  const float* r00 = p0 + i0 * 64;
  const float* r01 = p0 + i1 * 64;
  const float* r10 = p1 + i0 * 64;
  const float* r11 = p1 + i1 * 64;
  float bv = bias_t[co];

  float2 res;
#pragma unroll
  for (int e = 0; e < 2; ++e) {
    int j = 2 * q + e;
    float pj = (float)j * R;
    float j0f = floorf(pj);
    int j0 = (int)j0f;
    int j1 = min(j0 + 1, 63);
    float g = pj - j0f;
    float a  = fmaxf(r00[j0] + r10[j0] + bv, 0.f);
    float bb = fmaxf(r00[j1] + r10[j1] + bv, 0.f);
    float cc = fmaxf(r01[j0] + r11[j0] + bv, 0.f);
    float dd = fmaxf(r01[j1] + r11[j1] + bv, 0.f);
    float t0 = a * (1.f - f) + cc * f;
    float t1 = bb * (1.f - f) + dd * f;
    float v = t0 * (1.f - g) + t1 * g;
    if (e == 0) res.x = v; else res.y = v;
  }
  *(float2*)&out[(size_t)bc * 16384 + i * 128 + 2 * q] = res;
}

extern "C" void kernel_launch(void* const* d_in, const int* in_sizes, int n_in,
                              void* d_out, int out_size, void* d_ws, size_t ws_size,
                              hipStream_t stream)
{
  const float* x     = (const float*)d_in[0];
  const float* w_off = (const float*)d_in[1];
  const float* b_off = (const float*)d_in[2];
  const float* w_dcn = (const float*)d_in[3];
  const float* b_dcn = (const float*)d_in[4];
  const float* gamma = (const float*)d_in[5];
  const float* beta  = (const float*)d_in[6];
  const float* rmean = (const float*)d_in[7];
  const float* rvar  = (const float*)d_in[8];
  float* out = (float*)d_out;

  char* ws = (char*)d_ws;
  size_t off = 0;
  auto alloc = [&](size_t bytes) {
    void* p = ws + off;
    off = (off + bytes + 255) & ~255UL;
    return p;
  };
  float*  om_part = (float*) alloc(sizeof(float)  * OCSPLIT * NB * 27 * HW);
  float4* md_w    = (float4*)alloc(sizeof(float4) * NB * 9 * HW);
  int4*   md_i    = (int4*)  alloc(sizeof(int4)   * NB * 9 * HW);
  unsigned short* w_hi = (unsigned short*)alloc(sizeof(unsigned short) * 9 * CIN * COUT);
  unsigned short* w_lo = (unsigned short*)alloc(sizeof(unsigned short) * 9 * CIN * COUT);
  unsigned short* wo_hi = (unsigned short*)alloc(sizeof(unsigned short) * 9 * 32 * 32 * 8);
  unsigned short* wo_lo = (unsigned short*)alloc(sizeof(unsigned short) * 9 * 32 * 32 * 8);
  float*  bias_t  = (float*) alloc(sizeof(float)  * COUT);
  float*  part    = (float*) alloc(sizeof(float)  * CSPLIT * NB * COUT * HW);
  (void)ws_size; (void)in_sizes; (void)n_in; (void)out_size;

  k_prep_w<<<(CIN * COUT * 9 + 255) / 256, 256, 0, stream>>>(
      w_dcn, b_dcn, gamma, beta, rmean, rvar, w_hi, w_lo, bias_t);
  k_prep_wo<<<(9 * 32 * 32 * 8 + 255) / 256, 256, 0, stream>>>(w_off, wo_hi, wo_lo);
  k_off_mfma<<<NB * 64 * 4, 256, 0, stream>>>(x, wo_hi, wo_lo, om_part);
  k_prep_md<<<(NB * 9 * HW + 255) / 256, 256, 0, stream>>>(om_part, b_off, md_w, md_i);
  k_dcn<<<CSPLIT * NB * 64, 256, 0, stream>>>(x, w_hi, w_lo, md_w, md_i, part);
  k_upred<<<(NB * COUT * 128 * 64 + 255) / 256, 256, 0, stream>>>(part, bias_t, out);
}

// Round 31
// 97.494 us; speedup vs baseline: 1.1891x; 1.0326x over previous
//
#include <hip/hip_runtime.h>
#include <math.h>

#define CIN  256
#define COUT 128
#define HW   4096
#define NB   4
#define OCSPLIT 4
#define CSPLIT  2
#define CPC  (CIN / CSPLIT)      // 128 channels per k_dcn block (4 chunks of 32)
#define SFLAV (576 * 16)         // u32 words in k_dcn sbuf (hi flavor only)

typedef short short8v __attribute__((ext_vector_type(8)));
typedef float f32x4  __attribute__((ext_vector_type(4)));

// ---------------- merged weight prep: DCN hi/lo split + offset-conv pack + bias
__global__ __launch_bounds__(256) void k_prep(
    const float* __restrict__ w_dcn, const float* __restrict__ b_dcn,
    const float* __restrict__ gamma, const float* __restrict__ beta,
    const float* __restrict__ rmean, const float* __restrict__ rvar,
    const float* __restrict__ w_off,
    unsigned short* __restrict__ w_hi, unsigned short* __restrict__ w_lo,
    unsigned short* __restrict__ wo_hi, unsigned short* __restrict__ wo_lo,
    float* __restrict__ bias_t)
{
  int t = blockIdx.x * 256 + threadIdx.x;
  if (t < COUT) {
    float sc = gamma[t] * rsqrtf(rvar[t] + 1e-5f);
    bias_t[t] = b_dcn[t] * sc + beta[t] - rmean[t] * sc;
  }
  if (t < 9 * 32 * 32 * 8) {   // offset-conv weights: [k][cq][co32][8ch], co>=27 zero
    int ce = t & 7;
    int co = (t >> 3) & 31;
    int cq = (t >> 8) & 31;
    int k  = t >> 13;
    int c = cq * 8 + ce;
    float w = (co < 27) ? w_off[((size_t)co * CIN + c) * 9 + k] : 0.f;
    unsigned int wb = __float_as_uint(w);
    unsigned short hi = (unsigned short)(wb >> 16);
    float lof = w - __uint_as_float(wb & 0xFFFF0000u);
    unsigned short lo = (unsigned short)(__float_as_uint(lof) >> 16);
    wo_hi[t] = hi;
    wo_lo[t] = lo;
  }
  if (t >= CIN * COUT * 9) return;
  int k = t % 9;
  int q = t / 9;
  int co = q % COUT;
  int c  = q / COUT;
  float sc = gamma[co] * rsqrtf(rvar[co] + 1e-5f);
  float w = w_dcn[((size_t)co * CIN + c) * 9 + k] * sc;
  unsigned int wb = __float_as_uint(w);
  unsigned short hi = (unsigned short)(wb >> 16);
  float lof = w - __uint_as_float(wb & 0xFFFF0000u);
  unsigned short lo = (unsigned short)(__float_as_uint(lof) >> 16);
  size_t idx = (((size_t)k * 32 + (c >> 3)) * 128 + co) * 8 + (c & 7);
  w_hi[idx] = hi;
  w_lo[idx] = lo;
}

// ---------------- offset conv via MFMA: x rounded bf16 (2-term), W hi/lo split
// + XCD swizzle (grid 1024 = 8 x 128). LDS 15840 B.  (R30, validated)
__global__ __launch_bounds__(256, 4) void k_off_mfma(
    const float* __restrict__ x,
    const unsigned short* __restrict__ wo_hi, const unsigned short* __restrict__ wo_lo,
    float* __restrict__ om_part)
{
  int blk = (blockIdx.x & 7) * 128 + (blockIdx.x >> 3);  // bijective: 1024 = 8*128
  int split = blk & 3;
  int bh = blk >> 2;
  int b = bh >> 6, h = bh & 63;
  int t = threadIdx.x;
  int lane = t & 63;
  int wv = t >> 6;
  int lrow = lane & 15, lgrp = lane >> 4;

  __shared__ __align__(16) unsigned int win_hi[3 * 66 * 20];  // 15840 B

  f32x4 acc[2];
  acc[0] = (f32x4){0.f, 0.f, 0.f, 0.f};
  acc[1] = (f32x4){0.f, 0.f, 0.f, 0.f};

  const float* xb = x + (size_t)b * CIN * HW;

  for (int chunk = 0; chunk < 2; ++chunk) {
    int cbase = split * 64 + chunk * 32;
    for (int i = t; i < 3168; i += 256) {
      int cp = i / 198;
      int s  = i - cp * 198;
      int r  = s / 66;
      int colp = s - r * 66;
      int row = h + r - 1;
      int col = colp - 1;
      bool v = ((unsigned)row < 64u) && ((unsigned)col < 64u);
      int ch = cbase + 2 * cp;
      float f0 = 0.f, f1 = 0.f;
      if (v) {
        const float* xp = xb + ((size_t)ch * 64 + row) * 64 + col;
        f0 = xp[0];
        f1 = xp[HW];
      }
      unsigned a0 = __float_as_uint(f0) + 0x8000u;   // round-to-nearest bf16
      unsigned a1 = __float_as_uint(f1) + 0x8000u;
      win_hi[s * 20 + cp] = (a0 >> 16) | (a1 & 0xFFFF0000u);
    }
    __syncthreads();

    int pos = wv * 16 + lrow;
#pragma unroll
    for (int k = 0; k < 9; ++k) {
      int ky = k / 3 - 1, kx = k % 3 - 1;
      int slot = (ky + 1) * 66 + pos + kx + 1;
      short8v bhv = *(const short8v*)&win_hi[slot * 20 + lgrp * 4];
#pragma unroll
      for (int m = 0; m < 2; ++m) {
        size_t widx = (((size_t)k * 32 + (cbase >> 3) + lgrp) * 32 + m * 16 + lrow) * 8;
        short8v ah = *(const short8v*)(wo_hi + widx);
        short8v al = *(const short8v*)(wo_lo + widx);
        acc[m] = __builtin_amdgcn_mfma_f32_16x16x32_bf16(ah, bhv, acc[m], 0, 0, 0);
        acc[m] = __builtin_amdgcn_mfma_f32_16x16x32_bf16(al, bhv, acc[m], 0, 0, 0);
      }
    }
    __syncthreads();
  }

  int pos = wv * 16 + lrow;
#pragma unroll
  for (int m = 0; m < 2; ++m)
#pragma unroll
    for (int j = 0; j < 4; ++j) {
      int co = m * 16 + lgrp * 4 + j;
      if (co < 27)
        om_part[(((size_t)split * NB + b) * 27 + co) * HW + h * 64 + pos] = acc[m][j];
    }
}

// ---------------- DCN: P=64 channel-last LDS window + MFMA (R25/R28 structure)
// md computed INLINE from om_part (k_prep_md fused; bit-identical arithmetic).
__global__ __launch_bounds__(256, 3) void k_dcn(
    const float* __restrict__ x,
    const unsigned short* __restrict__ w_hi, const unsigned short* __restrict__ w_lo,
    const float* __restrict__ om_part, const float* __restrict__ b_off,
    float* __restrict__ part)
{
  int blk = (blockIdx.x & 7) * 64 + (blockIdx.x >> 3);  // bijective: 512 = 8*64
  int h = blk & 63;
  int b = (blk >> 6) & (NB - 1);
  int s2 = blk >> 8;
  int c0 = s2 * CPC;
  int t = threadIdx.x;
  int lane = t & 63;
  int wv = t >> 6;
  int lrow = lane & 15, lgrp = lane >> 4;

  __shared__ __align__(16) unsigned int sbuf[SFLAV];      // 36864 B (hi only)
  __shared__ __align__(16) float win[8 * 64 * 4];         // 8192 B, channel-last

  int W0 = min(max(h - 3, 0), 56);
  int ob = W0 * 64;

  // ---- inline md computation (verbatim k_prep_md math; bit-identical)
#define MDCALC(K, POS, MW, MI)                                                  \
  {                                                                             \
    int k_ = (K);                                                               \
    int hw_ = h * 64 + (POS);                                                   \
    int w_ = hw_ & 63;                                                          \
    float dy = b_off[2 * k_], dx = b_off[2 * k_ + 1], mr = b_off[18 + k_];      \
    _Pragma("unroll")                                                           \
    for (int s_ = 0; s_ < OCSPLIT; ++s_) {                                      \
      size_t o_ = ((size_t)s_ * NB + b) * 27 * HW + hw_;                        \
      dy += om_part[o_ + (size_t)(2 * k_) * HW];                                \
      dx += om_part[o_ + (size_t)(2 * k_ + 1) * HW];                            \
      mr += om_part[o_ + (size_t)(18 + k_) * HW];                               \
    }                                                                           \
    float m_ = 1.0f / (1.0f + expf(-mr));                                       \
    int ky_ = k_ / 3 - 1, kx_ = k_ % 3 - 1;                                     \
    float py_ = dy + (float)h + (float)ky_;                                     \
    float px_ = dx + (float)w_ + (float)kx_;                                    \
    float y0f_ = floorf(py_), x0f_ = floorf(px_);                               \
    float fy_ = py_ - y0f_, fx_ = px_ - x0f_;                                   \
    int y0_ = (int)y0f_, x0_ = (int)x0f_;                                       \
    int y1_ = y0_ + 1, x1_ = x0_ + 1;                                           \
    bool vy0_ = (y0_ >= 0) & (y0_ < 64), vy1_ = (y1_ >= 0) & (y1_ < 64);        \
    bool vx0_ = (x0_ >= 0) & (x0_ < 64), vx1_ = (x1_ >= 0) & (x1_ < 64);        \
    int cy0_ = min(max(y0_, 0), 63), cy1_ = min(max(y1_, 0), 63);               \
    int cx0_ = min(max(x0_, 0), 63), cx1_ = min(max(x1_, 0), 63);               \
    MW.x = (vy0_ && vx0_) ? (1.f - fy_) * (1.f - fx_) * m_ : 0.f;               \
    MW.y = (vy0_ && vx1_) ? (1.f - fy_) * fx_ * m_ : 0.f;                       \
    MW.z = (vy1_ && vx0_) ? fy_ * (1.f - fx_) * m_ : 0.f;                       \
    MW.w = (vy1_ && vx1_) ? fy_ * fx_ * m_ : 0.f;                               \
    MI.x = cy0_ * 64 + cx0_;                                                    \
    MI.y = cy0_ * 64 + cx1_;                                                    \
    MI.z = cy1_ * 64 + cx0_;                                                    \
    MI.w = cy1_ * 64 + cx1_;                                                    \
  }

  int k0 = t >> 6;
  float4 mw0; int4 mi0;
  float4 mw1; int4 mi1;
  MDCALC(k0, (t & 63), mw0, mi0)
  MDCALC(k0 + 4, (t & 63), mw1, mi1)
  bool hasC = (t < 64);
  float4 mw2 = make_float4(0.f, 0.f, 0.f, 0.f);
  int4  mi2 = make_int4(0, 0, 0, 0);
  if (hasC) MDCALC(8, t, mw2, mi2)
#undef MDCALC

  int fast0 = __all(((unsigned)(mi0.x - ob) < 512u) && ((unsigned)(mi0.z - ob) < 512u));
  int fast1 = __all(((unsigned)(mi1.x - ob) < 512u) && ((unsigned)(mi1.z - ob) < 512u));
  int fast2 = __all(((unsigned)(mi2.x - ob) < 512u) && ((unsigned)(mi2.z - ob) < 512u));

  f32x4 acc[2][4];
#pragma unroll
  for (int m = 0; m < 2; ++m)
#pragma unroll
    for (int nt = 0; nt < 4; ++nt)
      acc[m][nt] = (f32x4){0.f, 0.f, 0.f, 0.f};

  const float* xb = x + (size_t)b * CIN * HW;

// pack S as round-to-nearest bf16 pairs, single flavor
#define GATHER(MW, MI, FASTE, ROW)                                              \
  {                                                                             \
    float s0_, s1_, s2_, s3_;                                                   \
    if (FASTE) {                                                                \
      float4 T0 = *(const float4*)&win[(MI.x - ob) * 4];                        \
      float4 T1 = *(const float4*)&win[(MI.y - ob) * 4];                        \
      float4 T2 = *(const float4*)&win[(MI.z - ob) * 4];                        \
      float4 T3 = *(const float4*)&win[(MI.w - ob) * 4];                        \
      s0_ = MW.x * T0.x + MW.y * T1.x + MW.z * T2.x + MW.w * T3.x;              \
      s1_ = MW.x * T0.y + MW.y * T1.y + MW.z * T2.y + MW.w * T3.y;              \
      s2_ = MW.x * T0.z + MW.y * T1.z + MW.z * T2.z + MW.w * T3.z;              \
      s3_ = MW.x * T0.w + MW.y * T1.w + MW.z * T2.w + MW.w * T3.w;              \
    } else {                                                                    \
      const float* xc_ = xb + (size_t)c4 * HW;                                  \
      s0_ = MW.x * xc_[MI.x] + MW.y * xc_[MI.y] + MW.z * xc_[MI.z] + MW.w * xc_[MI.w]; \
      xc_ += HW;                                                                \
      s1_ = MW.x * xc_[MI.x] + MW.y * xc_[MI.y] + MW.z * xc_[MI.z] + MW.w * xc_[MI.w]; \
      xc_ += HW;                                                                \
      s2_ = MW.x * xc_[MI.x] + MW.y * xc_[MI.y] + MW.z * xc_[MI.z] + MW.w * xc_[MI.w]; \
      xc_ += HW;                                                                \
      s3_ = MW.x * xc_[MI.x] + MW.y * xc_[MI.y] + MW.z * xc_[MI.z] + MW.w * xc_[MI.w]; \
    }                                                                           \
    unsigned a0_ = __float_as_uint(s0_) + 0x8000u;                              \
    unsigned a1_ = __float_as_uint(s1_) + 0x8000u;                              \
    unsigned a2_ = __float_as_uint(s2_) + 0x8000u;                              \
    unsigned a3_ = __float_as_uint(s3_) + 0x8000u;                              \
    unsigned hiA_ = (a0_ >> 16) | (a1_ & 0xFFFF0000u);                          \
    unsigned hiB_ = (a2_ >> 16) | (a3_ & 0xFFFF0000u);                          \
    int cp0_ = 2 * step;                                                        \
    int quad_ = (((ROW) >> 2) + (cp0_ >> 2)) & 3;                               \
    int word_ = (ROW) * 16 + quad_ * 4 + (cp0_ & 3);                            \
    *(uint2*)&sbuf[word_] = make_uint2(hiA_, hiB_);                             \
  }

  for (int chunk = 0; chunk < CPC / 32; ++chunk) {
    int cbase = c0 + chunk * 32;
    for (int step = 0; step < 8; ++step) {
      int c4 = cbase + step * 4;
      {
        const float* xsb = xb + (size_t)(c4 + (t & 3)) * HW + ob + (t >> 2);
        int ldsbase = t & ~63;    // wave-uniform
#pragma unroll
        for (int j = 0; j < 8; ++j)
          __builtin_amdgcn_global_load_lds(
              (const __attribute__((address_space(1))) void*)(xsb + j * 64),
              (__attribute__((address_space(3))) void*)&win[j * 256 + ldsbase],
              4, 0, 0);
      }
      __syncthreads();
      GATHER(mw0, mi0, fast0, t)
      GATHER(mw1, mi1, fast1, 256 + t)
      if (hasC) GATHER(mw2, mi2, fast2, 512 + t)
      __syncthreads();
    }

    __builtin_amdgcn_s_setprio(1);
#pragma unroll
    for (int k = 0; k < 9; ++k) {
      short8v bh[4];
#pragma unroll
      for (int nt = 0; nt < 4; ++nt) {
        int row = k * 64 + nt * 16 + lrow;
        int quad = ((row >> 2) + lgrp) & 3;
        bh[nt] = *(const short8v*)&sbuf[row * 16 + quad * 4];
      }
#pragma unroll
      for (int m = 0; m < 2; ++m) {
        size_t widx = (((size_t)k * 32 + (cbase >> 3) + lgrp) * 128 + (wv * 32 + m * 16 + lrow)) * 8;
        short8v ah = *(const short8v*)(w_hi + widx);
        short8v al = *(const short8v*)(w_lo + widx);
#pragma unroll
        for (int nt = 0; nt < 4; ++nt) {
          acc[m][nt] = __builtin_amdgcn_mfma_f32_16x16x32_bf16(ah, bh[nt], acc[m][nt], 0, 0, 0);
          acc[m][nt] = __builtin_amdgcn_mfma_f32_16x16x32_bf16(al, bh[nt], acc[m][nt], 0, 0, 0);
        }
      }
    }
    __builtin_amdgcn_s_setprio(0);
    __syncthreads();
  }
#undef GATHER

#pragma unroll
  for (int m = 0; m < 2; ++m)
#pragma unroll
    for (int nt = 0; nt < 4; ++nt)
#pragma unroll
      for (int j = 0; j < 4; ++j) {
        int co = wv * 32 + m * 16 + lgrp * 4 + j;
        int p = h * 64 + nt * 16 + lrow;
        part[(((size_t)s2 * NB + b) * COUT + co) * HW + p] = acc[m][nt][j];
      }
}

// ---------------- fused reduce + bias + relu + 2x bilinear upsample
// j-pair tiled (R29, validated) + XCD swizzle (grid 16384 = 8 x 2048).
__global__ __launch_bounds__(256) void k_upred(
    const float* __restrict__ part, const float* __restrict__ bias_t,
    float* __restrict__ out)
{
  int bid = (blockIdx.x & 7) * 2048 + (blockIdx.x >> 3);  // bijective: 16384 = 8*2048
  int t = bid * 256 + threadIdx.x;
  if (t >= NB * COUT * 128 * 64) return;
  int q = t & 63;
  int i = (t >> 6) & 127;
  int bc = t >> 13;                 // b*COUT + co
  int co = bc & (COUT - 1);
  const float R = (float)(63.0 / 127.0);
  float pi = (float)i * R;
  float i0f = floorf(pi);
  int i0 = (int)i0f;
  int i1 = min(i0 + 1, 63);
  float f = pi - i0f;

  const float* p0 = part + (size_t)bc * HW;
  const float* p1 = part + (size_t)(CSPLIT - 1) * NB * COUT * HW + (size_t)bc * HW;
  const float* r00 = p0 + i0 * 64;
  const float* r01 = p0 + i1 * 64;
  const float* r10 = p1 + i0 * 64;
  const float* r11 = p1 + i1 * 64;
  float bv = bias_t[co];

  float2 res;
#pragma unroll
  for (int e = 0; e < 2; ++e) {
    int j = 2 * q + e;
    float pj = (float)j * R;
    float j0f = floorf(pj);
    int j0 = (int)j0f;
    int j1 = min(j0 + 1, 63);
    float g = pj - j0f;
    float a  = fmaxf(r00[j0] + r10[j0] + bv, 0.f);
    float bb = fmaxf(r00[j1] + r10[j1] + bv, 0.f);
    float cc = fmaxf(r01[j0] + r11[j0] + bv, 0.f);
    float dd = fmaxf(r01[j1] + r11[j1] + bv, 0.f);
    float t0 = a * (1.f - f) + cc * f;
    float t1 = bb * (1.f - f) + dd * f;
    float v = t0 * (1.f - g) + t1 * g;
    if (e == 0) res.x = v; else res.y = v;
  }
  *(float2*)&out[(size_t)bc * 16384 + i * 128 + 2 * q] = res;
}

extern "C" void kernel_launch(void* const* d_in, const int* in_sizes, int n_in,
                              void* d_out, int out_size, void* d_ws, size_t ws_size,
                              hipStream_t stream)
{
  const float* x     = (const float*)d_in[0];
  const float* w_off = (const float*)d_in[1];
  const float* b_off = (const float*)d_in[2];
  const float* w_dcn = (const float*)d_in[3];
  const float* b_dcn = (const float*)d_in[4];
  const float* gamma = (const float*)d_in[5];
  const float* beta  = (const float*)d_in[6];
  const float* rmean = (const float*)d_in[7];
  const float* rvar  = (const float*)d_in[8];
  float* out = (float*)d_out;

  char* ws = (char*)d_ws;
  size_t off = 0;
  auto alloc = [&](size_t bytes) {
    void* p = ws + off;
    off = (off + bytes + 255) & ~255UL;
    return p;
  };
  float*  om_part = (float*) alloc(sizeof(float)  * OCSPLIT * NB * 27 * HW);
  unsigned short* w_hi = (unsigned short*)alloc(sizeof(unsigned short) * 9 * CIN * COUT);
  unsigned short* w_lo = (unsigned short*)alloc(sizeof(unsigned short) * 9 * CIN * COUT);
  unsigned short* wo_hi = (unsigned short*)alloc(sizeof(unsigned short) * 9 * 32 * 32 * 8);
  unsigned short* wo_lo = (unsigned short*)alloc(sizeof(unsigned short) * 9 * 32 * 32 * 8);
  float*  bias_t  = (float*) alloc(sizeof(float)  * COUT);
  float*  part    = (float*) alloc(sizeof(float)  * CSPLIT * NB * COUT * HW);
  (void)ws_size; (void)in_sizes; (void)n_in; (void)out_size;

  k_prep<<<(CIN * COUT * 9 + 255) / 256, 256, 0, stream>>>(
      w_dcn, b_dcn, gamma, beta, rmean, rvar, w_off, w_hi, w_lo, wo_hi, wo_lo, bias_t);
  k_off_mfma<<<NB * 64 * 4, 256, 0, stream>>>(x, wo_hi, wo_lo, om_part);
  k_dcn<<<CSPLIT * NB * 64, 256, 0, stream>>>(x, w_hi, w_lo, om_part, b_off, part);
  k_upred<<<(NB * COUT * 128 * 64 + 255) / 256, 256, 0, stream>>>(part, bias_t, out);
}